// Round 2
// baseline (3328.872 us; speedup 1.0000x reference)
//
#include <hip/hip_runtime.h>

#define NN 50000
#define NE 800000
#define DIM 128
#define NHEADS 2

typedef unsigned int uint;

// f[n][j] = sum_k h[n][k] * W[k][j]  (all f32).
// Block: 256 threads -> 64 rows x 128 cols tile, k chunked by 32.
// LDS: Ws 32x132 + hsm 64x33 ~= 26 KB.
__global__ __launch_bounds__(256) void gemm128(
    const float* __restrict__ h, const float* __restrict__ W,
    float* __restrict__ f, int n)
{
    __shared__ float Ws[32][132];
    __shared__ float hsm[64][33];
    const int tid = threadIdx.x;
    const int rg = tid >> 4;   // 0..15 -> rows rg*4..+3
    const int cg = tid & 15;   // cols cg*8..+7
    const long row0 = (long)blockIdx.x * 64;

    float acc[4][8];
#pragma unroll
    for (int i = 0; i < 4; i++)
#pragma unroll
        for (int j = 0; j < 8; j++) acc[i][j] = 0.0f;

    for (int k0 = 0; k0 < 128; k0 += 32) {
        __syncthreads();
        // stage W chunk: rows k0..k0+31 x 128 cols = 1024 float4
        {
            const float4* Wg = (const float4*)(W + (size_t)k0 * 128);
#pragma unroll
            for (int i = 0; i < 4; i++) {
                const int idx = tid + 256 * i;   // 0..1023
                const int r = idx >> 5;          // chunk row
                const int c = idx & 31;          // float4 col
                const float4 v = Wg[idx];
                Ws[r][c * 4 + 0] = v.x; Ws[r][c * 4 + 1] = v.y;
                Ws[r][c * 4 + 2] = v.z; Ws[r][c * 4 + 3] = v.w;
            }
        }
        // stage h chunk: 64 rows x 32 k-cols; thread: row tid>>2, 8 floats
        {
            const int r = tid >> 2;
            const int c = tid & 3;
            const long nrow = row0 + r;
            float4 a = make_float4(0.f, 0.f, 0.f, 0.f), b = a;
            if (nrow < n) {
                const float4* hp = (const float4*)(h + nrow * DIM + k0 + c * 8);
                a = hp[0]; b = hp[1];
            }
            float* dp = &hsm[r][c * 8];
            dp[0] = a.x; dp[1] = a.y; dp[2] = a.z; dp[3] = a.w;
            dp[4] = b.x; dp[5] = b.y; dp[6] = b.z; dp[7] = b.w;
        }
        __syncthreads();
#pragma unroll
        for (int k = 0; k < 32; k++) {
            const float hv0 = hsm[rg * 4 + 0][k];
            const float hv1 = hsm[rg * 4 + 1][k];
            const float hv2 = hsm[rg * 4 + 2][k];
            const float hv3 = hsm[rg * 4 + 3][k];
            const float* wr = &Ws[k][cg * 8];
#pragma unroll
            for (int j = 0; j < 8; j++) {
                const float wv = wr[j];
                acc[0][j] += hv0 * wv;
                acc[1][j] += hv1 * wv;
                acc[2][j] += hv2 * wv;
                acc[3][j] += hv3 * wv;
            }
        }
    }

#pragma unroll
    for (int i = 0; i < 4; i++) {
        const long nr = row0 + rg * 4 + i;
        if (nr < n) {
            float4* op = (float4*)(f + nr * DIM + cg * 8);
            op[0] = make_float4(acc[i][0], acc[i][1], acc[i][2], acc[i][3]);
            op[1] = make_float4(acc[i][4], acc[i][5], acc[i][6], acc[i][7]);
        }
    }
}

// el[n][h] = sum_d f[n][h][d]*al[h][d]; er likewise. One thread per (node, head).
__global__ __launch_bounds__(256) void node_scores(
    const float* __restrict__ f, const float* __restrict__ al,
    const float* __restrict__ ar, float* __restrict__ el,
    float* __restrict__ er, int n)
{
    const int g = blockIdx.x * 256 + threadIdx.x;
    if (g >= n * NHEADS) return;
    const int node = g >> 1, head = g & 1;
    const float4* fr  = (const float4*)(f + (size_t)node * DIM + head * 64);
    const float4* alp = (const float4*)(al + head * 64);
    const float4* arp = (const float4*)(ar + head * 64);
    float sl = 0.f, sr = 0.f;
#pragma unroll
    for (int i = 0; i < 16; i++) {
        const float4 fv = fr[i], av = alp[i], rv = arp[i];
        sl += fv.x * av.x + fv.y * av.y + fv.z * av.z + fv.w * av.w;
        sr += fv.x * rv.x + fv.y * rv.y + fv.z * rv.z + fv.w * rv.w;
    }
    el[g] = sl; er[g] = sr;
}

// Per edge: e = leakyrelu(el[src]+er[dst]); ex = exp(e); sden[dst] += ex.
// (No segment-max: scores are O(1), exp cannot overflow; ratio is identical.)
__global__ __launch_bounds__(256) void edge_scores(
    const int* __restrict__ src, const int* __restrict__ dst,
    const float2* __restrict__ el, const float2* __restrict__ er,
    float2* __restrict__ ex, float* __restrict__ sden, int ne)
{
    const int e = blockIdx.x * 256 + threadIdx.x;
    if (e >= ne) return;
    const int s = src[e], d = dst[e];
    const float2 a = el[s], b = er[d];
    float e0 = a.x + b.x, e1 = a.y + b.y;
    e0 = e0 > 0.f ? e0 : 0.2f * e0;
    e1 = e1 > 0.f ? e1 : 0.2f * e1;
    const float x0 = __expf(e0), x1 = __expf(e1);
    ex[e] = make_float2(x0, x1);
    unsafeAtomicAdd(sden + 2 * d, x0);
    unsafeAtomicAdd(sden + 2 * d + 1, x1);
}

// Wave per edge: agg[dst][h][d] += f[src][h][d] * ex[e][h]/sden[dst][h].
// Lane l covers feats 2l,2l+1 (head = l/32). 128 f32 atomics per edge.
__global__ __launch_bounds__(256) void edge_aggregate(
    const int* __restrict__ src, const int* __restrict__ dst,
    const float2* __restrict__ ex, const float2* __restrict__ sden,
    const float* __restrict__ f, float* __restrict__ agg, int ne)
{
    const int w = blockIdx.x * 4 + (threadIdx.x >> 6);
    if (w >= ne) return;
    const int lane = threadIdx.x & 63;
    const int s = src[w], d = dst[w];
    const float2 exv = ex[w];
    const float2 sd = sden[d];
    const float a = (lane < 32) ? (exv.x / sd.x) : (exv.y / sd.y);
    const float2 fv = *(const float2*)(f + (size_t)s * DIM + 2 * lane);
    float* dp = agg + (size_t)d * DIM + 2 * lane;
    unsafeAtomicAdd(dp,     fv.x * a);
    unsafeAtomicAdd(dp + 1, fv.y * a);
}

__device__ __forceinline__ float elu(float v) { return v > 0.f ? v : expm1f(v); }

// acc = elu(agg + b)   (first relation overwrites)
__global__ __launch_bounds__(256) void post_first(
    const float* __restrict__ agg, const float* __restrict__ b,
    float* __restrict__ acc, int total)
{
    const int i = blockIdx.x * 256 + threadIdx.x;
    if (i >= total) return;
    acc[i] = elu(agg[i] + b[i & 127]);
}

// out = acc + elu(agg + b)   (second relation finishes layer; f32 out)
__global__ __launch_bounds__(256) void post_second(
    const float* __restrict__ agg, const float* __restrict__ b,
    const float* __restrict__ acc, float* __restrict__ out, int total)
{
    const int i = blockIdx.x * 256 + threadIdx.x;
    if (i >= total) return;
    out[i] = acc[i] + elu(agg[i] + b[i & 127]);
}

extern "C" void kernel_launch(void* const* d_in, const int* in_sizes, int n_in,
                              void* d_out, int out_size, void* d_ws, size_t ws_size,
                              hipStream_t stream)
{
    const float* x   = (const float*)d_in[0];
    const float* W0  = (const float*)d_in[1];
    const float* al0 = (const float*)d_in[2];
    const float* ar0 = (const float*)d_in[3];
    const float* b0  = (const float*)d_in[4];
    const float* W1  = (const float*)d_in[5];
    const float* al1 = (const float*)d_in[6];
    const float* ar1 = (const float*)d_in[7];
    const float* b1  = (const float*)d_in[8];
    const int* src0 = (const int*)d_in[9];
    const int* dst0 = (const int*)d_in[10];
    const int* src1 = (const int*)d_in[11];
    const int* dst1 = (const int*)d_in[12];
    float* out = (float*)d_out;

    char* w = (char*)d_ws;
    auto alloc = [&](size_t bytes) {
        char* p = w; w += (bytes + 255) & ~(size_t)255; return p;
    };
    float* fbuf = (float*)alloc((size_t)NN * DIM * 4);
    float* h1   = (float*)alloc((size_t)NN * DIM * 4);
    float* agg  = (float*)alloc((size_t)NN * DIM * 4);
    float* acc  = (float*)alloc((size_t)NN * DIM * 4);
    float* ex   = (float*)alloc((size_t)NE * 2 * 4);
    float* el   = (float*)alloc((size_t)NN * 2 * 4);
    float* er   = (float*)alloc((size_t)NN * 2 * 4);
    float* sden = (float*)alloc((size_t)NN * 2 * 4);

    const int total = NN * DIM;
    for (int L = 0; L < 2; L++) {
        const float* hin = L ? h1 : x;
        const float* W   = L ? W1 : W0;
        const float* al  = L ? al1 : al0;
        const float* ar  = L ? ar1 : ar0;
        const float* b   = L ? b1 : b0;
        const int* src = L ? src1 : src0;
        const int* dst = L ? dst1 : dst0;
        for (int r = 0; r < 2; r++) {
            gemm128<<<(NN + 63) / 64, 256, 0, stream>>>(
                hin, W + (size_t)r * DIM * DIM, fbuf, NN);
            node_scores<<<(NN * NHEADS + 255) / 256, 256, 0, stream>>>(
                fbuf, al + r * DIM, ar + r * DIM, el, er, NN);
            hipMemsetAsync(sden, 0, (size_t)NN * 2 * 4, stream);
            edge_scores<<<(NE + 255) / 256, 256, 0, stream>>>(
                src + (size_t)r * NE, dst + (size_t)r * NE,
                (const float2*)el, (const float2*)er, (float2*)ex, sden, NE);
            hipMemsetAsync(agg, 0, (size_t)NN * DIM * 4, stream);
            edge_aggregate<<<(NE + 3) / 4, 256, 0, stream>>>(
                src + (size_t)r * NE, dst + (size_t)r * NE,
                (const float2*)ex, (const float2*)sden, fbuf, agg, NE);
            if (r == 0)
                post_first<<<(total + 255) / 256, 256, 0, stream>>>(agg, b, acc, total);
            else
                post_second<<<(total + 255) / 256, 256, 0, stream>>>(
                    agg, b + DIM, acc, L ? out : h1, total);
        }
    }
}

// Round 3
// 1636.177 us; speedup vs baseline: 2.0345x; 2.0345x over previous
//
#include <hip/hip_runtime.h>

#define NN 50000
#define NE 800000
#define DIM 128
#define NHEADS 2

typedef unsigned int uint;

// f[n][j] = sum_k h[n][k] * W[k][j]  (all f32).
// Block: 256 threads -> 64 rows x 128 cols tile, k chunked by 32.
__global__ __launch_bounds__(256) void gemm128(
    const float* __restrict__ h, const float* __restrict__ W,
    float* __restrict__ f, int n)
{
    __shared__ float Ws[32][132];
    __shared__ float hsm[64][33];
    const int tid = threadIdx.x;
    const int rg = tid >> 4;
    const int cg = tid & 15;
    const long row0 = (long)blockIdx.x * 64;

    float acc[4][8];
#pragma unroll
    for (int i = 0; i < 4; i++)
#pragma unroll
        for (int j = 0; j < 8; j++) acc[i][j] = 0.0f;

    for (int k0 = 0; k0 < 128; k0 += 32) {
        __syncthreads();
        {
            const float4* Wg = (const float4*)(W + (size_t)k0 * 128);
#pragma unroll
            for (int i = 0; i < 4; i++) {
                const int idx = tid + 256 * i;
                const int r = idx >> 5;
                const int c = idx & 31;
                const float4 v = Wg[idx];
                Ws[r][c * 4 + 0] = v.x; Ws[r][c * 4 + 1] = v.y;
                Ws[r][c * 4 + 2] = v.z; Ws[r][c * 4 + 3] = v.w;
            }
        }
        {
            const int r = tid >> 2;
            const int c = tid & 3;
            const long nrow = row0 + r;
            float4 a = make_float4(0.f, 0.f, 0.f, 0.f), b = a;
            if (nrow < n) {
                const float4* hp = (const float4*)(h + nrow * DIM + k0 + c * 8);
                a = hp[0]; b = hp[1];
            }
            float* dp = &hsm[r][c * 8];
            dp[0] = a.x; dp[1] = a.y; dp[2] = a.z; dp[3] = a.w;
            dp[4] = b.x; dp[5] = b.y; dp[6] = b.z; dp[7] = b.w;
        }
        __syncthreads();
#pragma unroll
        for (int k = 0; k < 32; k++) {
            const float hv0 = hsm[rg * 4 + 0][k];
            const float hv1 = hsm[rg * 4 + 1][k];
            const float hv2 = hsm[rg * 4 + 2][k];
            const float hv3 = hsm[rg * 4 + 3][k];
            const float* wr = &Ws[k][cg * 8];
#pragma unroll
            for (int j = 0; j < 8; j++) {
                const float wv = wr[j];
                acc[0][j] += hv0 * wv;
                acc[1][j] += hv1 * wv;
                acc[2][j] += hv2 * wv;
                acc[3][j] += hv3 * wv;
            }
        }
    }

#pragma unroll
    for (int i = 0; i < 4; i++) {
        const long nr = row0 + rg * 4 + i;
        if (nr < n) {
            float4* op = (float4*)(f + nr * DIM + cg * 8);
            op[0] = make_float4(acc[i][0], acc[i][1], acc[i][2], acc[i][3]);
            op[1] = make_float4(acc[i][4], acc[i][5], acc[i][6], acc[i][7]);
        }
    }
}

// el[n][h] = sum_d f[n][h][d]*al[h][d]; er likewise. One thread per (node, head).
__global__ __launch_bounds__(256) void node_scores(
    const float* __restrict__ f, const float* __restrict__ al,
    const float* __restrict__ ar, float* __restrict__ el,
    float* __restrict__ er, int n)
{
    const int g = blockIdx.x * 256 + threadIdx.x;
    if (g >= n * NHEADS) return;
    const int node = g >> 1, head = g & 1;
    const float4* fr  = (const float4*)(f + (size_t)node * DIM + head * 64);
    const float4* alp = (const float4*)(al + head * 64);
    const float4* arp = (const float4*)(ar + head * 64);
    float sl = 0.f, sr = 0.f;
#pragma unroll
    for (int i = 0; i < 16; i++) {
        const float4 fv = fr[i], av = alp[i], rv = arp[i];
        sl += fv.x * av.x + fv.y * av.y + fv.z * av.z + fv.w * av.w;
        sr += fv.x * rv.x + fv.y * rv.y + fv.z * rv.z + fv.w * rv.w;
    }
    el[g] = sl; er[g] = sr;
}

// Per edge: e = leakyrelu(el[src]+er[dst]); ex = exp(e); sden[dst] += ex.
// (No segment-max: scores are O(1), exp cannot overflow; ratio is identical.)
__global__ __launch_bounds__(256) void edge_scores(
    const int* __restrict__ src, const int* __restrict__ dst,
    const float2* __restrict__ el, const float2* __restrict__ er,
    float2* __restrict__ ex, float* __restrict__ sden, int ne)
{
    const int e = blockIdx.x * 256 + threadIdx.x;
    if (e >= ne) return;
    const int s = src[e], d = dst[e];
    const float2 a = el[s], b = er[d];
    float e0 = a.x + b.x, e1 = a.y + b.y;
    e0 = e0 > 0.f ? e0 : 0.2f * e0;
    e1 = e1 > 0.f ? e1 : 0.2f * e1;
    const float x0 = __expf(e0), x1 = __expf(e1);
    ex[e] = make_float2(x0, x1);
    unsafeAtomicAdd(sden + 2 * d, x0);
    unsafeAtomicAdd(sden + 2 * d + 1, x1);
}

// ---- CSR build (all 4 edge sets at once; set es = layer*2 + relation) ----

__global__ __launch_bounds__(256) void count_deg(
    const int* __restrict__ dst0, const int* __restrict__ dst1,
    int* __restrict__ deg)
{
    const int g = blockIdx.x * 256 + threadIdx.x;
    if (g >= 4 * NE) return;
    const int es = g / NE, e = g - es * NE;
    const int* d = (es < 2) ? (dst0 + (size_t)es * NE) : (dst1 + (size_t)(es - 2) * NE);
    atomicAdd(deg + es * NN + d[e], 1);
}

// One block per edge set: exclusive scan of deg -> row (NN+1) and cursor copy.
__global__ __launch_bounds__(1024) void scan_deg(
    const int* __restrict__ deg, int* __restrict__ row, int* __restrict__ cursor)
{
    __shared__ int lds[1024];
    __shared__ int carry;
    const int b = blockIdx.x;
    const int* dg = deg + b * NN;
    int* rw = row + b * (NN + 1);
    int* cu = cursor + b * NN;
    if (threadIdx.x == 0) carry = 0;
    __syncthreads();
    for (int base = 0; base < NN; base += 1024) {
        const int i = base + threadIdx.x;
        const int v = (i < NN) ? dg[i] : 0;
        lds[threadIdx.x] = v;
        __syncthreads();
        for (int off = 1; off < 1024; off <<= 1) {
            const int t = (threadIdx.x >= off) ? lds[threadIdx.x - off] : 0;
            __syncthreads();
            lds[threadIdx.x] += t;
            __syncthreads();
        }
        const int excl = lds[threadIdx.x] - v + carry;
        if (i < NN) { rw[i] = excl; cu[i] = excl; }
        __syncthreads();
        if (threadIdx.x == 0) carry += lds[1023];
        __syncthreads();
    }
    if (threadIdx.x == 0) rw[NN] = carry;
}

__global__ __launch_bounds__(256) void scatter_edges(
    const int* __restrict__ dst0, const int* __restrict__ dst1,
    int* __restrict__ cursor, int* __restrict__ csr_eid)
{
    const int g = blockIdx.x * 256 + threadIdx.x;
    if (g >= 4 * NE) return;
    const int es = g / NE, e = g - es * NE;
    const int* d = (es < 2) ? (dst0 + (size_t)es * NE) : (dst1 + (size_t)(es - 2) * NE);
    const int p = atomicAdd(cursor + es * NN + d[e], 1);
    csr_eid[(size_t)es * NE + p] = e;
}

__device__ __forceinline__ float elu(float v) { return v > 0.f ? v : expm1f(v); }

// Wave per dst node: gather-aggregate over incoming edges (no atomics), fused
// epilogue. mode 0: outp = elu(agg + b). mode 1: outp = accin + elu(agg + b).
__global__ __launch_bounds__(256) void aggregate_csr(
    const int* __restrict__ row, const int* __restrict__ csr_eid,
    const int* __restrict__ src, const float2* __restrict__ ex,
    const float2* __restrict__ sden, const float* __restrict__ f,
    const float* __restrict__ bias, const float* __restrict__ accin,
    float* __restrict__ outp, int mode)
{
    const int wv = (blockIdx.x * 256 + threadIdx.x) >> 6;
    if (wv >= NN) return;
    const int lane = threadIdx.x & 63;
    const int beg = row[wv], end = row[wv + 1];
    const float2 sd = sden[wv];
    const float den = (lane < 32) ? sd.x : sd.y;
    const float inv = 1.0f / den;          // unused (inf) when deg==0
    float2 acc = make_float2(0.f, 0.f);
    for (int j = beg; j < end; j++) {
        const int e = csr_eid[j];
        const int s = src[e];
        const float2 x = ex[e];
        const float a = ((lane < 32) ? x.x : x.y) * inv;
        const float2 fv = *(const float2*)(f + (size_t)s * DIM + 2 * lane);
        acc.x += fv.x * a;
        acc.y += fv.y * a;
    }
    const float b0 = bias[2 * lane], b1 = bias[2 * lane + 1];
    float o0 = elu(acc.x + b0);
    float o1 = elu(acc.y + b1);
    float* op = outp + (size_t)wv * DIM + 2 * lane;
    if (mode) {
        const float2 ap = *(const float2*)(accin + (size_t)wv * DIM + 2 * lane);
        o0 += ap.x; o1 += ap.y;
    }
    op[0] = o0; op[1] = o1;
}

extern "C" void kernel_launch(void* const* d_in, const int* in_sizes, int n_in,
                              void* d_out, int out_size, void* d_ws, size_t ws_size,
                              hipStream_t stream)
{
    const float* x   = (const float*)d_in[0];
    const float* W0  = (const float*)d_in[1];
    const float* al0 = (const float*)d_in[2];
    const float* ar0 = (const float*)d_in[3];
    const float* b0  = (const float*)d_in[4];
    const float* W1  = (const float*)d_in[5];
    const float* al1 = (const float*)d_in[6];
    const float* ar1 = (const float*)d_in[7];
    const float* b1  = (const float*)d_in[8];
    const int* src0 = (const int*)d_in[9];
    const int* dst0 = (const int*)d_in[10];
    const int* src1 = (const int*)d_in[11];
    const int* dst1 = (const int*)d_in[12];
    float* out = (float*)d_out;

    char* w = (char*)d_ws;
    auto alloc = [&](size_t bytes) {
        char* p = w; w += (bytes + 255) & ~(size_t)255; return p;
    };
    float* fbuf   = (float*)alloc((size_t)NN * DIM * 4);
    float* h1     = (float*)alloc((size_t)NN * DIM * 4);
    float* accbuf = (float*)alloc((size_t)NN * DIM * 4);
    float* ex     = (float*)alloc((size_t)NE * 2 * 4);
    float* el     = (float*)alloc((size_t)NN * 2 * 4);
    float* er     = (float*)alloc((size_t)NN * 2 * 4);
    float* sden   = (float*)alloc((size_t)NN * 2 * 4);
    int*   deg    = (int*)alloc((size_t)4 * NN * 4);
    int*   row    = (int*)alloc((size_t)4 * (NN + 1) * 4);
    int*   cursor = (int*)alloc((size_t)4 * NN * 4);
    int*   csr    = (int*)alloc((size_t)4 * NE * 4);

    // ---- CSR build for all 4 edge sets ----
    hipMemsetAsync(deg, 0, (size_t)4 * NN * 4, stream);
    count_deg<<<(4 * NE + 255) / 256, 256, 0, stream>>>(dst0, dst1, deg);
    scan_deg<<<4, 1024, 0, stream>>>(deg, row, cursor);
    scatter_edges<<<(4 * NE + 255) / 256, 256, 0, stream>>>(dst0, dst1, cursor, csr);

    for (int L = 0; L < 2; L++) {
        const float* hin = L ? h1 : x;
        const float* W   = L ? W1 : W0;
        const float* al  = L ? al1 : al0;
        const float* ar  = L ? ar1 : ar0;
        const float* b   = L ? b1 : b0;
        const int* src = L ? src1 : src0;
        for (int r = 0; r < 2; r++) {
            const int es = L * 2 + r;
            gemm128<<<(NN + 63) / 64, 256, 0, stream>>>(
                hin, W + (size_t)r * DIM * DIM, fbuf, NN);
            node_scores<<<(NN * NHEADS + 255) / 256, 256, 0, stream>>>(
                fbuf, al + r * DIM, ar + r * DIM, el, er, NN);
            hipMemsetAsync(sden, 0, (size_t)NN * 2 * 4, stream);
            edge_scores<<<(NE + 255) / 256, 256, 0, stream>>>(
                src + (size_t)r * NE,
                (L ? dst1 : dst0) + (size_t)r * NE,
                (const float2*)el, (const float2*)er, (float2*)ex, sden, NE);
            aggregate_csr<<<(NN * 64 + 255) / 256, 256, 0, stream>>>(
                row + es * (NN + 1), csr + (size_t)es * NE,
                src + (size_t)r * NE, (const float2*)ex, (const float2*)sden,
                fbuf, b + r * DIM,
                accbuf, (r == 0) ? accbuf : (L ? out : h1), r);
        }
    }
}

// Round 5
// 733.297 us; speedup vs baseline: 4.5396x; 2.2313x over previous
//
#include <hip/hip_runtime.h>

#define NN 50000
#define NE 800000
#define DIM 128
#define NB 128          // dst buckets for binned CSR build
#define CH 2048         // edges per bin_edges block

typedef unsigned int uint;

// ---------------- dense GEMM: f = h @ W (f32) ----------------
__global__ __launch_bounds__(256) void gemm128(
    const float* __restrict__ h, const float* __restrict__ W,
    float* __restrict__ f, int n)
{
    __shared__ float Ws[32][132];
    __shared__ float hsm[64][33];
    const int tid = threadIdx.x;
    const int rg = tid >> 4;
    const int cg = tid & 15;
    const long row0 = (long)blockIdx.x * 64;

    float acc[4][8];
#pragma unroll
    for (int i = 0; i < 4; i++)
#pragma unroll
        for (int j = 0; j < 8; j++) acc[i][j] = 0.0f;

    for (int k0 = 0; k0 < 128; k0 += 32) {
        __syncthreads();
        {
            const float4* Wg = (const float4*)(W + (size_t)k0 * 128);
#pragma unroll
            for (int i = 0; i < 4; i++) {
                const int idx = tid + 256 * i;
                const int r = idx >> 5;
                const int c = idx & 31;
                const float4 v = Wg[idx];
                Ws[r][c * 4 + 0] = v.x; Ws[r][c * 4 + 1] = v.y;
                Ws[r][c * 4 + 2] = v.z; Ws[r][c * 4 + 3] = v.w;
            }
        }
        {
            const int r = tid >> 2;
            const int c = tid & 3;
            const long nrow = row0 + r;
            float4 a = make_float4(0.f, 0.f, 0.f, 0.f), b = a;
            if (nrow < n) {
                const float4* hp = (const float4*)(h + nrow * DIM + k0 + c * 8);
                a = hp[0]; b = hp[1];
            }
            float* dp = &hsm[r][c * 8];
            dp[0] = a.x; dp[1] = a.y; dp[2] = a.z; dp[3] = a.w;
            dp[4] = b.x; dp[5] = b.y; dp[6] = b.z; dp[7] = b.w;
        }
        __syncthreads();
#pragma unroll
        for (int k = 0; k < 32; k++) {
            const float hv0 = hsm[rg * 4 + 0][k];
            const float hv1 = hsm[rg * 4 + 1][k];
            const float hv2 = hsm[rg * 4 + 2][k];
            const float hv3 = hsm[rg * 4 + 3][k];
            const float* wr = &Ws[k][cg * 8];
#pragma unroll
            for (int j = 0; j < 8; j++) {
                const float wv = wr[j];
                acc[0][j] += hv0 * wv;
                acc[1][j] += hv1 * wv;
                acc[2][j] += hv2 * wv;
                acc[3][j] += hv3 * wv;
            }
        }
    }

#pragma unroll
    for (int i = 0; i < 4; i++) {
        const long nr = row0 + rg * 4 + i;
        if (nr < n) {
            float4* op = (float4*)(f + nr * DIM + cg * 8);
            op[0] = make_float4(acc[i][0], acc[i][1], acc[i][2], acc[i][3]);
            op[1] = make_float4(acc[i][4], acc[i][5], acc[i][6], acc[i][7]);
        }
    }
}

// ---------------- node attention scores ----------------
__global__ __launch_bounds__(256) void node_scores(
    const float* __restrict__ f, const float* __restrict__ al,
    const float* __restrict__ ar, float* __restrict__ el,
    float* __restrict__ er, int n)
{
    const int g = blockIdx.x * 256 + threadIdx.x;
    if (g >= n * 2) return;
    const int node = g >> 1, head = g & 1;
    const float4* fr  = (const float4*)(f + (size_t)node * DIM + head * 64);
    const float4* alp = (const float4*)(al + head * 64);
    const float4* arp = (const float4*)(ar + head * 64);
    float sl = 0.f, sr = 0.f;
#pragma unroll
    for (int i = 0; i < 16; i++) {
        const float4 fv = fr[i], av = alp[i], rv = arp[i];
        sl += fv.x * av.x + fv.y * av.y + fv.z * av.z + fv.w * av.w;
        sr += fv.x * rv.x + fv.y * rv.y + fv.z * rv.z + fv.w * rv.w;
    }
    el[g] = sl; er[g] = sr;
}

// ---------------- CSR build ----------------
__global__ __launch_bounds__(256) void count_deg(
    const int* __restrict__ dst0, const int* __restrict__ dst1,
    int* __restrict__ deg)
{
    const int g = blockIdx.x * 256 + threadIdx.x;
    if (g >= 4 * NE) return;
    const int es = g / NE, e = g - es * NE;
    const int* d = (es < 2) ? (dst0 + (size_t)es * NE) : (dst1 + (size_t)(es - 2) * NE);
    atomicAdd(deg + es * NN + d[e], 1);
}

#define CHN 1024
#define NCH 49   // ceil(NN/CHN)

__global__ __launch_bounds__(256) void deg_partials(
    const int* __restrict__ deg, int* __restrict__ psum)
{
    __shared__ int ws[4];
    const int bid = blockIdx.x;
    const int s = bid / NCH, c = bid - s * NCH;
    const int base = c * CHN + threadIdx.x * 4;
    const int* dg = deg + s * NN;
    int v = 0;
#pragma unroll
    for (int k = 0; k < 4; k++) {
        const int i = base + k;
        if (i < NN) v += dg[i];
    }
    for (int o = 32; o > 0; o >>= 1) v += __shfl_xor(v, o);
    if ((threadIdx.x & 63) == 0) ws[threadIdx.x >> 6] = v;
    __syncthreads();
    if (threadIdx.x == 0) psum[bid] = ws[0] + ws[1] + ws[2] + ws[3];
}

__global__ __launch_bounds__(256) void scan_partials(
    const int* __restrict__ psum, int* __restrict__ chunkoff)
{
    const int w = threadIdx.x >> 6, lane = threadIdx.x & 63;
    int v = (lane < NCH) ? psum[w * NCH + lane] : 0;
    int incl = v;
    for (int o = 1; o < 64; o <<= 1) {
        const int t = __shfl_up(incl, o);
        if (lane >= o) incl += t;
    }
    if (lane < NCH) chunkoff[w * NCH + lane] = incl - v;
}

__global__ __launch_bounds__(256) void write_row(
    const int* __restrict__ deg, const int* __restrict__ chunkoff,
    int* __restrict__ row)
{
    __shared__ int tsum[256];
    const int bid = blockIdx.x;
    const int s = bid / NCH, c = bid - s * NCH;
    const int* dg = deg + s * NN;
    int* rw = row + s * (NN + 1);
    const int base = c * CHN + threadIdx.x * 4;
    int v[4];
    int tot = 0;
#pragma unroll
    for (int k = 0; k < 4; k++) {
        const int i = base + k;
        v[k] = (i < NN) ? dg[i] : 0;
        tot += v[k];
    }
    tsum[threadIdx.x] = tot;
    __syncthreads();
    for (int o = 1; o < 256; o <<= 1) {
        const int t = (threadIdx.x >= o) ? tsum[threadIdx.x - o] : 0;
        __syncthreads();
        tsum[threadIdx.x] += t;
        __syncthreads();
    }
    int excl = tsum[threadIdx.x] - tot + chunkoff[bid];
#pragma unroll
    for (int k = 0; k < 4; k++) {
        const int i = base + k;
        if (i < NN) rw[i] = excl;
        excl += v[k];
    }
    if (threadIdx.x == 0 && c == 0) rw[NN] = NE;
}

__global__ __launch_bounds__(512) void init_gcur(
    const int* __restrict__ row, int* __restrict__ gcur)
{
    const int i = threadIdx.x;
    const int s = i >> 7, b = i & (NB - 1);
    const int nb0 = (b * NN + NB - 1) / NB;
    gcur[i] = row[s * (NN + 1) + nb0];
}

// Pass A: bin edges by dst bucket with LDS staging. Payload = {dst, src}.
// binned is PER-SET: binned[s*NE + pos].
__global__ __launch_bounds__(256) void bin_edges(
    const int* __restrict__ dst0, const int* __restrict__ dst1,
    const int* __restrict__ src0, const int* __restrict__ src1,
    int* __restrict__ gcur, int2* __restrict__ binned)
{
    __shared__ int hist[NB], ebase[NB], lcur[NB], gbase[NB], sc[NB];
    __shared__ int2 stage[CH];
    const int bpset = (NE + CH - 1) / CH;
    const int bid = blockIdx.x;
    const int s = bid / bpset, cb = bid - s * bpset;
    const int* dstp = (s < 2) ? (dst0 + (size_t)s * NE) : (dst1 + (size_t)(s - 2) * NE);
    const int* srcp = (s < 2) ? (src0 + (size_t)s * NE) : (src1 + (size_t)(s - 2) * NE);
    const int e0 = cb * CH;
    const int t = threadIdx.x;

    if (t < NB) hist[t] = 0;
    __syncthreads();

    int myd[8], mys[8];
#pragma unroll
    for (int k = 0; k < 8; k++) {
        const int e = e0 + t + k * 256;
        if (e < NE) {
            const int d = dstp[e];
            myd[k] = d;
            mys[k] = srcp[e];
            atomicAdd(&hist[(d * NB) / NN], 1);
        } else myd[k] = -1;
    }
    __syncthreads();
    if (t < NB) sc[t] = hist[t];
    __syncthreads();
    for (int o = 1; o < NB; o <<= 1) {
        int tv = 0;
        if (t < NB && t >= o) tv = sc[t - o];
        __syncthreads();
        if (t < NB) sc[t] += tv;
        __syncthreads();
    }
    if (t < NB) {
        ebase[t] = sc[t] - hist[t];
        lcur[t]  = sc[t] - hist[t];
        gbase[t] = atomicAdd(&gcur[s * NB + t], hist[t]);
    }
    __syncthreads();
#pragma unroll
    for (int k = 0; k < 8; k++) {
        if (myd[k] >= 0) {
            const int b = (myd[k] * NB) / NN;
            const int p = atomicAdd(&lcur[b], 1);
            stage[p] = make_int2(myd[k], mys[k]);
        }
    }
    __syncthreads();
    int2* bset = binned + (size_t)s * NE;
    const int total = ebase[NB - 1] + hist[NB - 1];
    for (int i = t; i < total; i += 256) {
        const int2 v = stage[i];
        const int b = (v.x * NB) / NN;
        bset[gbase[b] + (i - ebase[b])] = v;
    }
}

// Pass B: per (set,bucket) positional scatter with LDS cursors.
__global__ __launch_bounds__(256) void build_csr(
    const int* __restrict__ row, const int2* __restrict__ binned,
    int* __restrict__ csr_src)
{
    __shared__ int lcur[392];
    const int bid = blockIdx.x;
    const int s = bid >> 7, b = bid & (NB - 1);
    const int nb0 = (b * NN + NB - 1) / NB;
    int nb1 = ((b + 1) * NN + NB - 1) / NB;
    if (nb1 > NN) nb1 = NN;
    const int* rw = row + s * (NN + 1);
    for (int i = threadIdx.x; i < nb1 - nb0; i += 256) lcur[i] = rw[nb0 + i];
    __syncthreads();
    const int jb = rw[nb0], je = rw[nb1];
    const int2* bset = binned + (size_t)s * NE;
    int* outp = csr_src + (size_t)s * NE;
    for (int j = jb + threadIdx.x; j < je; j += 256) {
        const int2 v = bset[j];
        const int p = atomicAdd(&lcur[v.x - nb0], 1);
        outp[p] = v.y;
    }
}

__device__ __forceinline__ float elu(float v) { return v > 0.f ? v : expm1f(v); }

// ---------------- fused softmax + aggregate ----------------
// Wave per dst node; two passes over its edge segment.
// mode 0: outp = elu(agg+b). mode 1: outp = accin + elu(agg+b).
__global__ __launch_bounds__(256) void aggregate_fused(
    const int* __restrict__ row, const int* __restrict__ csr_src,
    const float2* __restrict__ el, const float2* __restrict__ er,
    const float* __restrict__ f, const float* __restrict__ bias,
    const float* __restrict__ accin, float* __restrict__ outp, int mode)
{
    const int wv = (blockIdx.x * 256 + threadIdx.x) >> 6;
    if (wv >= NN) return;
    const int lane = threadIdx.x & 63;
    const int beg = row[wv], end = row[wv + 1];
    const float2 erd = er[wv];

    float den0 = 0.f, den1 = 0.f;
    for (int c0 = beg; c0 < end; c0 += 64) {
        const int j = c0 + lane;
        if (j < end) {
            const float2 els = el[csr_src[j]];
            float e0 = els.x + erd.x, e1 = els.y + erd.y;
            e0 = e0 > 0.f ? e0 : 0.2f * e0;
            e1 = e1 > 0.f ? e1 : 0.2f * e1;
            den0 += __expf(e0);
            den1 += __expf(e1);
        }
    }
    for (int o = 32; o > 0; o >>= 1) {
        den0 += __shfl_xor(den0, o);
        den1 += __shfl_xor(den1, o);
    }
    const float inv0 = 1.0f / den0, inv1 = 1.0f / den1;  // unused when deg==0

    float2 acc = make_float2(0.f, 0.f);
    for (int c0 = beg; c0 < end; c0 += 64) {
        const int j = c0 + lane;
        int s = -1;
        float ex0 = 0.f, ex1 = 0.f;
        if (j < end) {
            s = csr_src[j];
            const float2 els = el[s];
            float e0 = els.x + erd.x, e1 = els.y + erd.y;
            e0 = e0 > 0.f ? e0 : 0.2f * e0;
            e1 = e1 > 0.f ? e1 : 0.2f * e1;
            ex0 = __expf(e0) * inv0;
            ex1 = __expf(e1) * inv1;
        }
        const int cm = min(64, end - c0);
        for (int tt = 0; tt < cm; tt++) {
            const int st = __shfl(s, tt);
            const float a0 = __shfl(ex0, tt);
            const float a1 = __shfl(ex1, tt);
            const float aa = (lane < 32) ? a0 : a1;
            const float2 fv = *(const float2*)(f + (size_t)st * DIM + 2 * lane);
            acc.x += fv.x * aa;
            acc.y += fv.y * aa;
        }
    }

    const float b0 = bias[2 * lane], b1 = bias[2 * lane + 1];
    float o0 = elu(acc.x + b0);
    float o1 = elu(acc.y + b1);
    float* op = outp + (size_t)wv * DIM + 2 * lane;
    if (mode) {
        const float2 ap = *(const float2*)(accin + (size_t)wv * DIM + 2 * lane);
        o0 += ap.x; o1 += ap.y;
    }
    op[0] = o0; op[1] = o1;
}

extern "C" void kernel_launch(void* const* d_in, const int* in_sizes, int n_in,
                              void* d_out, int out_size, void* d_ws, size_t ws_size,
                              hipStream_t stream)
{
    const float* x   = (const float*)d_in[0];
    const float* W0  = (const float*)d_in[1];
    const float* al0 = (const float*)d_in[2];
    const float* ar0 = (const float*)d_in[3];
    const float* b0  = (const float*)d_in[4];
    const float* W1  = (const float*)d_in[5];
    const float* al1 = (const float*)d_in[6];
    const float* ar1 = (const float*)d_in[7];
    const float* b1  = (const float*)d_in[8];
    const int* src0 = (const int*)d_in[9];
    const int* dst0 = (const int*)d_in[10];
    const int* src1 = (const int*)d_in[11];
    const int* dst1 = (const int*)d_in[12];
    float* out = (float*)d_out;

    char* w = (char*)d_ws;
    auto alloc = [&](size_t bytes) {
        char* p = w; w += (bytes + 255) & ~(size_t)255; return p;
    };
    float* fbuf   = (float*)alloc((size_t)NN * DIM * 4);   // aliased as binned during CSR build
    float* h1     = (float*)alloc((size_t)NN * DIM * 4);
    float* accbuf = (float*)alloc((size_t)NN * DIM * 4);
    float* el     = (float*)alloc((size_t)NN * 2 * 4);
    float* er     = (float*)alloc((size_t)NN * 2 * 4);
    int*   deg    = (int*)alloc((size_t)4 * NN * 4);
    int*   row    = (int*)alloc((size_t)4 * (NN + 1) * 4);
    int*   csr    = (int*)alloc((size_t)4 * NE * 4);
    int*   psum   = (int*)alloc((size_t)4 * NCH * 4);
    int*   coff   = (int*)alloc((size_t)4 * NCH * 4);
    int*   gcur   = (int*)alloc((size_t)4 * NB * 4);
    int2*  binned = (int2*)fbuf;   // 4*NE*8 = 25.6MB == fbuf size; consumed before first gemm

    // ---- CSR build (positions depend only on dst indices) ----
    hipMemsetAsync(deg, 0, (size_t)4 * NN * 4, stream);
    count_deg<<<(4 * NE + 255) / 256, 256, 0, stream>>>(dst0, dst1, deg);
    deg_partials<<<4 * NCH, 256, 0, stream>>>(deg, psum);
    scan_partials<<<1, 256, 0, stream>>>(psum, coff);
    write_row<<<4 * NCH, 256, 0, stream>>>(deg, coff, row);
    init_gcur<<<1, 512, 0, stream>>>(row, gcur);
    {
        const int bpset = (NE + CH - 1) / CH;
        bin_edges<<<4 * bpset, 256, 0, stream>>>(dst0, dst1, src0, src1, gcur, binned);
    }
    build_csr<<<4 * NB, 256, 0, stream>>>(row, binned, csr);

    for (int L = 0; L < 2; L++) {
        const float* hin = L ? h1 : x;
        const float* W   = L ? W1 : W0;
        const float* al  = L ? al1 : al0;
        const float* ar  = L ? ar1 : ar0;
        const float* b   = L ? b1 : b0;
        for (int r = 0; r < 2; r++) {
            const int es = L * 2 + r;
            gemm128<<<(NN + 63) / 64, 256, 0, stream>>>(
                hin, W + (size_t)r * DIM * DIM, fbuf, NN);
            node_scores<<<(NN * 2 + 255) / 256, 256, 0, stream>>>(
                fbuf, al + r * DIM, ar + r * DIM, el, er, NN);
            aggregate_fused<<<(NN * 64 + 255) / 256, 256, 0, stream>>>(
                row + es * (NN + 1), csr + (size_t)es * NE,
                (const float2*)el, (const float2*)er, fbuf, b + r * DIM,
                accbuf, (r == 0) ? accbuf : (L ? out : h1), r);
        }
    }
}

// Round 6
// 618.745 us; speedup vs baseline: 5.3800x; 1.1851x over previous
//
#include <hip/hip_runtime.h>

#define NN 50000
#define NE 800000
#define DIM 128
#define NB 128          // dst buckets for binned CSR build
#define CH 2048         // edges per binning block

typedef unsigned int uint;

// ---------------- dense GEMM: f = h @ W (f32) ----------------
__global__ __launch_bounds__(256) void gemm128(
    const float* __restrict__ h, const float* __restrict__ W,
    float* __restrict__ f, int n)
{
    __shared__ float Ws[32][132];
    __shared__ float hsm[64][33];
    const int tid = threadIdx.x;
    const int rg = tid >> 4;
    const int cg = tid & 15;
    const long row0 = (long)blockIdx.x * 64;

    float acc[4][8];
#pragma unroll
    for (int i = 0; i < 4; i++)
#pragma unroll
        for (int j = 0; j < 8; j++) acc[i][j] = 0.0f;

    for (int k0 = 0; k0 < 128; k0 += 32) {
        __syncthreads();
        {
            const float4* Wg = (const float4*)(W + (size_t)k0 * 128);
#pragma unroll
            for (int i = 0; i < 4; i++) {
                const int idx = tid + 256 * i;
                const int r = idx >> 5;
                const int c = idx & 31;
                const float4 v = Wg[idx];
                Ws[r][c * 4 + 0] = v.x; Ws[r][c * 4 + 1] = v.y;
                Ws[r][c * 4 + 2] = v.z; Ws[r][c * 4 + 3] = v.w;
            }
        }
        {
            const int r = tid >> 2;
            const int c = tid & 3;
            const long nrow = row0 + r;
            float4 a = make_float4(0.f, 0.f, 0.f, 0.f), b = a;
            if (nrow < n) {
                const float4* hp = (const float4*)(h + nrow * DIM + k0 + c * 8);
                a = hp[0]; b = hp[1];
            }
            float* dp = &hsm[r][c * 8];
            dp[0] = a.x; dp[1] = a.y; dp[2] = a.z; dp[3] = a.w;
            dp[4] = b.x; dp[5] = b.y; dp[6] = b.z; dp[7] = b.w;
        }
        __syncthreads();
#pragma unroll
        for (int k = 0; k < 32; k++) {
            const float hv0 = hsm[rg * 4 + 0][k];
            const float hv1 = hsm[rg * 4 + 1][k];
            const float hv2 = hsm[rg * 4 + 2][k];
            const float hv3 = hsm[rg * 4 + 3][k];
            const float* wr = &Ws[k][cg * 8];
#pragma unroll
            for (int j = 0; j < 8; j++) {
                const float wv = wr[j];
                acc[0][j] += hv0 * wv;
                acc[1][j] += hv1 * wv;
                acc[2][j] += hv2 * wv;
                acc[3][j] += hv3 * wv;
            }
        }
    }

#pragma unroll
    for (int i = 0; i < 4; i++) {
        const long nr = row0 + rg * 4 + i;
        if (nr < n) {
            float4* op = (float4*)(f + nr * DIM + cg * 8);
            op[0] = make_float4(acc[i][0], acc[i][1], acc[i][2], acc[i][3]);
            op[1] = make_float4(acc[i][4], acc[i][5], acc[i][6], acc[i][7]);
        }
    }
}

// ---------------- node attention scores ----------------
__global__ __launch_bounds__(256) void node_scores(
    const float* __restrict__ f, const float* __restrict__ al,
    const float* __restrict__ ar, float* __restrict__ el,
    float* __restrict__ er, int n)
{
    const int g = blockIdx.x * 256 + threadIdx.x;
    if (g >= n * 2) return;
    const int node = g >> 1, head = g & 1;
    const float4* fr  = (const float4*)(f + (size_t)node * DIM + head * 64);
    const float4* alp = (const float4*)(al + head * 64);
    const float4* arp = (const float4*)(ar + head * 64);
    float sl = 0.f, sr = 0.f;
#pragma unroll
    for (int i = 0; i < 16; i++) {
        const float4 fv = fr[i], av = alp[i], rv = arp[i];
        sl += fv.x * av.x + fv.y * av.y + fv.z * av.z + fv.w * av.w;
        sr += fv.x * rv.x + fv.y * rv.y + fv.z * rv.z + fv.w * rv.w;
    }
    el[g] = sl; er[g] = sr;
}

// ---------------- CSR build (no global per-node counters) ----------------
// Pass 0: per-block LDS histogram of dst buckets -> global bucket counts.
__global__ __launch_bounds__(256) void bucket_hist(
    const int* __restrict__ dst0, const int* __restrict__ dst1,
    int* __restrict__ bcount)
{
    __shared__ int hist[NB];
    const int bpset = (NE + CH - 1) / CH;
    const int bid = blockIdx.x;
    const int s = bid / bpset, cb = bid - s * bpset;
    const int* dstp = (s < 2) ? (dst0 + (size_t)s * NE) : (dst1 + (size_t)(s - 2) * NE);
    const int e0 = cb * CH;
    const int t = threadIdx.x;
    if (t < NB) hist[t] = 0;
    __syncthreads();
#pragma unroll
    for (int k = 0; k < 8; k++) {
        const int e = e0 + t + k * 256;
        if (e < NE) atomicAdd(&hist[(dstp[e] * NB) / NN], 1);
    }
    __syncthreads();
    if (t < NB && hist[t]) atomicAdd(&bcount[s * NB + t], hist[t]);
}

// Pass 0.5: serial scan of 128 bucket counts per set (4 threads).
__global__ __launch_bounds__(64) void scan_buckets(
    const int* __restrict__ bcount, int* __restrict__ bbase,
    int* __restrict__ gcur, int* __restrict__ row)
{
    const int s = threadIdx.x;
    if (s < 4) {
        int acc = 0;
        for (int b = 0; b < NB; b++) {
            bbase[s * (NB + 1) + b] = acc;
            gcur[s * NB + b] = acc;
            acc += bcount[s * NB + b];
        }
        bbase[s * (NB + 1) + NB] = acc;   // == NE
        row[s * (NN + 1) + NN] = NE;
    }
}

// Pass A: bin edges by dst bucket with LDS staging. Payload = {dst, src}.
__global__ __launch_bounds__(256) void bin_edges(
    const int* __restrict__ dst0, const int* __restrict__ dst1,
    const int* __restrict__ src0, const int* __restrict__ src1,
    int* __restrict__ gcur, int2* __restrict__ binned)
{
    __shared__ int hist[NB], ebase[NB], lcur[NB], gbase[NB], sc[NB];
    __shared__ int2 stage[CH];
    const int bpset = (NE + CH - 1) / CH;
    const int bid = blockIdx.x;
    const int s = bid / bpset, cb = bid - s * bpset;
    const int* dstp = (s < 2) ? (dst0 + (size_t)s * NE) : (dst1 + (size_t)(s - 2) * NE);
    const int* srcp = (s < 2) ? (src0 + (size_t)s * NE) : (src1 + (size_t)(s - 2) * NE);
    const int e0 = cb * CH;
    const int t = threadIdx.x;

    if (t < NB) hist[t] = 0;
    __syncthreads();

    int myd[8], mys[8];
#pragma unroll
    for (int k = 0; k < 8; k++) {
        const int e = e0 + t + k * 256;
        if (e < NE) {
            const int d = dstp[e];
            myd[k] = d;
            mys[k] = srcp[e];
            atomicAdd(&hist[(d * NB) / NN], 1);
        } else myd[k] = -1;
    }
    __syncthreads();
    if (t < NB) sc[t] = hist[t];
    __syncthreads();
    for (int o = 1; o < NB; o <<= 1) {
        int tv = 0;
        if (t < NB && t >= o) tv = sc[t - o];
        __syncthreads();
        if (t < NB) sc[t] += tv;
        __syncthreads();
    }
    if (t < NB) {
        ebase[t] = sc[t] - hist[t];
        lcur[t]  = sc[t] - hist[t];
        gbase[t] = atomicAdd(&gcur[s * NB + t], hist[t]);
    }
    __syncthreads();
#pragma unroll
    for (int k = 0; k < 8; k++) {
        if (myd[k] >= 0) {
            const int b = (myd[k] * NB) / NN;
            const int p = atomicAdd(&lcur[b], 1);
            stage[p] = make_int2(myd[k], mys[k]);
        }
    }
    __syncthreads();
    int2* bset = binned + (size_t)s * NE;
    const int total = ebase[NB - 1] + hist[NB - 1];
    for (int i = t; i < total; i += 256) {
        const int2 v = stage[i];
        const int b = (v.x * NB) / NN;
        bset[gbase[b] + (i - ebase[b])] = v;
    }
}

// Pass B: per (set,bucket): LDS degree count + scan -> row[] write +
// positional scatter (all counters on-chip).
__global__ __launch_bounds__(256) void build_csr(
    const int* __restrict__ bbase, const int2* __restrict__ binned,
    int* __restrict__ row, int* __restrict__ csr_src)
{
    __shared__ int A[512], B[512], lcur[512];
    const int bid = blockIdx.x;
    const int s = bid >> 7, b = bid & (NB - 1);
    const int nb0 = (b * NN + NB - 1) / NB;
    int nb1 = ((b + 1) * NN + NB - 1) / NB;
    if (nb1 > NN) nb1 = NN;
    const int nloc = nb1 - nb0;
    const int jb = bbase[s * (NB + 1) + b], je = bbase[s * (NB + 1) + b + 1];
    const int t = threadIdx.x;

    A[t] = 0; A[t + 256] = 0;
    __syncthreads();
    const int2* bset = binned + (size_t)s * NE;
    for (int j = jb + t; j < je; j += 256)
        atomicAdd(&A[bset[j].x - nb0], 1);
    __syncthreads();
    const int c0 = A[t], c1 = A[t + 256];
    // inclusive Hillis-Steele over 512 (ping-pong)
    int* cur = A; int* nxt = B;
    for (int off = 1; off < 512; off <<= 1) {
        nxt[t]       = cur[t]       + ((t >= off)       ? cur[t - off]       : 0);
        nxt[t + 256] = cur[t + 256] + ((t + 256 >= off) ? cur[t + 256 - off] : 0);
        __syncthreads();
        int* tmp = cur; cur = nxt; nxt = tmp;
    }
    if (t < nloc) {
        const int v = jb + cur[t] - c0;
        lcur[t] = v;
        row[s * (NN + 1) + nb0 + t] = v;
    }
    if (t + 256 < nloc) {
        const int v = jb + cur[t + 256] - c1;
        lcur[t + 256] = v;
        row[s * (NN + 1) + nb0 + t + 256] = v;
    }
    __syncthreads();
    int* outp = csr_src + (size_t)s * NE;
    for (int j = jb + t; j < je; j += 256) {
        const int2 v = bset[j];
        const int p = atomicAdd(&lcur[v.x - nb0], 1);
        outp[p] = v.y;
    }
}

__device__ __forceinline__ float elu(float v) { return v > 0.f ? v : expm1f(v); }

// ---------------- fused softmax + aggregate ----------------
// Wave per dst node; two passes over its edge segment.
// mode 0: outp = elu(agg+b). mode 1: outp = accin + elu(agg+b).
__global__ __launch_bounds__(256) void aggregate_fused(
    const int* __restrict__ row, const int* __restrict__ csr_src,
    const float2* __restrict__ el, const float2* __restrict__ er,
    const float* __restrict__ f, const float* __restrict__ bias,
    const float* __restrict__ accin, float* __restrict__ outp, int mode)
{
    const int wv = (blockIdx.x * 256 + threadIdx.x) >> 6;
    if (wv >= NN) return;
    const int lane = threadIdx.x & 63;
    const int beg = row[wv], end = row[wv + 1];
    const float2 erd = er[wv];

    float den0 = 0.f, den1 = 0.f;
    for (int c0 = beg; c0 < end; c0 += 64) {
        const int j = c0 + lane;
        if (j < end) {
            const float2 els = el[csr_src[j]];
            float e0 = els.x + erd.x, e1 = els.y + erd.y;
            e0 = e0 > 0.f ? e0 : 0.2f * e0;
            e1 = e1 > 0.f ? e1 : 0.2f * e1;
            den0 += __expf(e0);
            den1 += __expf(e1);
        }
    }
    for (int o = 32; o > 0; o >>= 1) {
        den0 += __shfl_xor(den0, o);
        den1 += __shfl_xor(den1, o);
    }
    const float inv0 = 1.0f / den0, inv1 = 1.0f / den1;  // unused when deg==0

    float2 acc = make_float2(0.f, 0.f);
    for (int c0 = beg; c0 < end; c0 += 64) {
        const int j = c0 + lane;
        int s = -1;
        float ex0 = 0.f, ex1 = 0.f;
        if (j < end) {
            s = csr_src[j];
            const float2 els = el[s];
            float e0 = els.x + erd.x, e1 = els.y + erd.y;
            e0 = e0 > 0.f ? e0 : 0.2f * e0;
            e1 = e1 > 0.f ? e1 : 0.2f * e1;
            ex0 = __expf(e0) * inv0;
            ex1 = __expf(e1) * inv1;
        }
        const int cm = min(64, end - c0);
        for (int tt = 0; tt < cm; tt++) {
            const int st = __shfl(s, tt);
            const float a0 = __shfl(ex0, tt);
            const float a1 = __shfl(ex1, tt);
            const float aa = (lane < 32) ? a0 : a1;
            const float2 fv = *(const float2*)(f + (size_t)st * DIM + 2 * lane);
            acc.x += fv.x * aa;
            acc.y += fv.y * aa;
        }
    }

    const float b0 = bias[2 * lane], b1 = bias[2 * lane + 1];
    float o0 = elu(acc.x + b0);
    float o1 = elu(acc.y + b1);
    float* op = outp + (size_t)wv * DIM + 2 * lane;
    if (mode) {
        const float2 ap = *(const float2*)(accin + (size_t)wv * DIM + 2 * lane);
        o0 += ap.x; o1 += ap.y;
    }
    op[0] = o0; op[1] = o1;
}

extern "C" void kernel_launch(void* const* d_in, const int* in_sizes, int n_in,
                              void* d_out, int out_size, void* d_ws, size_t ws_size,
                              hipStream_t stream)
{
    const float* x   = (const float*)d_in[0];
    const float* W0  = (const float*)d_in[1];
    const float* al0 = (const float*)d_in[2];
    const float* ar0 = (const float*)d_in[3];
    const float* b0  = (const float*)d_in[4];
    const float* W1  = (const float*)d_in[5];
    const float* al1 = (const float*)d_in[6];
    const float* ar1 = (const float*)d_in[7];
    const float* b1  = (const float*)d_in[8];
    const int* src0 = (const int*)d_in[9];
    const int* dst0 = (const int*)d_in[10];
    const int* src1 = (const int*)d_in[11];
    const int* dst1 = (const int*)d_in[12];
    float* out = (float*)d_out;

    char* w = (char*)d_ws;
    auto alloc = [&](size_t bytes) {
        char* p = w; w += (bytes + 255) & ~(size_t)255; return p;
    };
    float* fbuf   = (float*)alloc((size_t)NN * DIM * 4);   // aliased as binned during CSR build
    float* h1     = (float*)alloc((size_t)NN * DIM * 4);
    float* accbuf = (float*)alloc((size_t)NN * DIM * 4);
    float* el     = (float*)alloc((size_t)NN * 2 * 4);
    float* er     = (float*)alloc((size_t)NN * 2 * 4);
    int*   row    = (int*)alloc((size_t)4 * (NN + 1) * 4);
    int*   csr    = (int*)alloc((size_t)4 * NE * 4);
    int*   bcount = (int*)alloc((size_t)4 * NB * 4);
    int*   bbase  = (int*)alloc((size_t)4 * (NB + 1) * 4);
    int*   gcur   = (int*)alloc((size_t)4 * NB * 4);
    int2*  binned = (int2*)fbuf;   // 4*NE*8 = 25.6MB == fbuf size; consumed before first gemm

    // ---- CSR build ----
    hipMemsetAsync(bcount, 0, (size_t)4 * NB * 4, stream);
    {
        const int bpset = (NE + CH - 1) / CH;
        bucket_hist<<<4 * bpset, 256, 0, stream>>>(dst0, dst1, bcount);
        scan_buckets<<<1, 64, 0, stream>>>(bcount, bbase, gcur, row);
        bin_edges<<<4 * bpset, 256, 0, stream>>>(dst0, dst1, src0, src1, gcur, binned);
    }
    build_csr<<<4 * NB, 256, 0, stream>>>(bbase, binned, row, csr);

    for (int L = 0; L < 2; L++) {
        const float* hin = L ? h1 : x;
        const float* W   = L ? W1 : W0;
        const float* al  = L ? al1 : al0;
        const float* ar  = L ? ar1 : ar0;
        const float* b   = L ? b1 : b0;
        for (int r = 0; r < 2; r++) {
            const int es = L * 2 + r;
            gemm128<<<(NN + 63) / 64, 256, 0, stream>>>(
                hin, W + (size_t)r * DIM * DIM, fbuf, NN);
            node_scores<<<(NN * 2 + 255) / 256, 256, 0, stream>>>(
                fbuf, al + r * DIM, ar + r * DIM, el, er, NN);
            aggregate_fused<<<(NN * 64 + 255) / 256, 256, 0, stream>>>(
                row + es * (NN + 1), csr + (size_t)es * NE,
                (const float2*)el, (const float2*)er, fbuf, b + r * DIM,
                accbuf, (r == 0) ? accbuf : (L ? out : h1), r);
        }
    }
}

// Round 7
// 549.853 us; speedup vs baseline: 6.0541x; 1.1253x over previous
//
#include <hip/hip_runtime.h>

#define NN 50000
#define NE 800000
#define DIM 128
#define NB 128          // dst buckets for binned CSR build
#define CH 2048         // edges per binning block

typedef unsigned int uint;
typedef unsigned short ushort;

__device__ __forceinline__ ushort f2bf(float f) {
    union { float f; uint i; } c; c.f = f;
    // round-to-nearest-even on the mantissa cut
    const uint r = (c.i + 0x7fffu + ((c.i >> 16) & 1u)) >> 16;
    return (ushort)r;
}

// ---------------- dense GEMM: fg(bf16) = h @ W; fused el/er epilogue --------
__global__ __launch_bounds__(256) void gemm128(
    const float* __restrict__ h, const float* __restrict__ W,
    const float* __restrict__ al, const float* __restrict__ ar,
    ushort* __restrict__ fg, float* __restrict__ el, float* __restrict__ er,
    int n)
{
    __shared__ float Ws[32][132];
    __shared__ float hsm[64][33];
    __shared__ float pel[64][17];
    __shared__ float per2[64][17];
    const int tid = threadIdx.x;
    const int rg = tid >> 4;
    const int cg = tid & 15;
    const long row0 = (long)blockIdx.x * 64;

    float alv[8], arv[8];
#pragma unroll
    for (int j = 0; j < 8; j++) {
        alv[j] = al[cg * 8 + j];
        arv[j] = ar[cg * 8 + j];
    }

    float acc[4][8];
#pragma unroll
    for (int i = 0; i < 4; i++)
#pragma unroll
        for (int j = 0; j < 8; j++) acc[i][j] = 0.0f;

    for (int k0 = 0; k0 < 128; k0 += 32) {
        __syncthreads();
        {
            const float4* Wg = (const float4*)(W + (size_t)k0 * 128);
#pragma unroll
            for (int i = 0; i < 4; i++) {
                const int idx = tid + 256 * i;
                const int r = idx >> 5;
                const int c = idx & 31;
                const float4 v = Wg[idx];
                Ws[r][c * 4 + 0] = v.x; Ws[r][c * 4 + 1] = v.y;
                Ws[r][c * 4 + 2] = v.z; Ws[r][c * 4 + 3] = v.w;
            }
        }
        {
            const int r = tid >> 2;
            const int c = tid & 3;
            const long nrow = row0 + r;
            float4 a = make_float4(0.f, 0.f, 0.f, 0.f), b = a;
            if (nrow < n) {
                const float4* hp = (const float4*)(h + nrow * DIM + k0 + c * 8);
                a = hp[0]; b = hp[1];
            }
            float* dp = &hsm[r][c * 8];
            dp[0] = a.x; dp[1] = a.y; dp[2] = a.z; dp[3] = a.w;
            dp[4] = b.x; dp[5] = b.y; dp[6] = b.z; dp[7] = b.w;
        }
        __syncthreads();
#pragma unroll
        for (int k = 0; k < 32; k++) {
            const float hv0 = hsm[rg * 4 + 0][k];
            const float hv1 = hsm[rg * 4 + 1][k];
            const float hv2 = hsm[rg * 4 + 2][k];
            const float hv3 = hsm[rg * 4 + 3][k];
            const float* wr = &Ws[k][cg * 8];
#pragma unroll
            for (int j = 0; j < 8; j++) {
                const float wv = wr[j];
                acc[0][j] += hv0 * wv;
                acc[1][j] += hv1 * wv;
                acc[2][j] += hv2 * wv;
                acc[3][j] += hv3 * wv;
            }
        }
    }

    // store bf16 feature rows + partial el/er into LDS
#pragma unroll
    for (int i = 0; i < 4; i++) {
        const int lrow = rg * 4 + i;
        const long nr = row0 + lrow;
        float sl = 0.f, sr = 0.f;
#pragma unroll
        for (int j = 0; j < 8; j++) {
            sl += acc[i][j] * alv[j];
            sr += acc[i][j] * arv[j];
        }
        pel[lrow][cg] = sl;
        per2[lrow][cg] = sr;
        if (nr < n) {
            ushort tmp[8];
#pragma unroll
            for (int j = 0; j < 8; j++) tmp[j] = f2bf(acc[i][j]);
            *(uint4*)(fg + (size_t)nr * DIM + cg * 8) = *(const uint4*)tmp;
        }
    }
    __syncthreads();
    // reduce 8 column-groups per (row, head); threads 0..127
    if (tid < 128) {
        const int lrow = tid >> 1, head = tid & 1;
        const long nr = row0 + lrow;
        if (nr < n) {
            float sl = 0.f, sr = 0.f;
#pragma unroll
            for (int k = 0; k < 8; k++) {
                sl += pel[lrow][head * 8 + k];
                sr += per2[lrow][head * 8 + k];
            }
            el[nr * 2 + head] = sl;
            er[nr * 2 + head] = sr;
        }
    }
}

// ---------------- CSR build (no global per-node counters) ----------------
__global__ __launch_bounds__(256) void bucket_hist(
    const int* __restrict__ dst0, const int* __restrict__ dst1,
    int* __restrict__ bcount)
{
    __shared__ int hist[NB];
    const int bpset = (NE + CH - 1) / CH;
    const int bid = blockIdx.x;
    const int s = bid / bpset, cb = bid - s * bpset;
    const int* dstp = (s < 2) ? (dst0 + (size_t)s * NE) : (dst1 + (size_t)(s - 2) * NE);
    const int e0 = cb * CH;
    const int t = threadIdx.x;
    if (t < NB) hist[t] = 0;
    __syncthreads();
#pragma unroll
    for (int k = 0; k < 8; k++) {
        const int e = e0 + t + k * 256;
        if (e < NE) atomicAdd(&hist[(dstp[e] * NB) / NN], 1);
    }
    __syncthreads();
    if (t < NB && hist[t]) atomicAdd(&bcount[s * NB + t], hist[t]);
}

__global__ __launch_bounds__(64) void scan_buckets(
    const int* __restrict__ bcount, int* __restrict__ bbase,
    int* __restrict__ gcur, int* __restrict__ row)
{
    const int s = threadIdx.x;
    if (s < 4) {
        int acc = 0;
        for (int b = 0; b < NB; b++) {
            bbase[s * (NB + 1) + b] = acc;
            gcur[s * NB + b] = acc;
            acc += bcount[s * NB + b];
        }
        bbase[s * (NB + 1) + NB] = acc;
        row[s * (NN + 1) + NN] = NE;
    }
}

__global__ __launch_bounds__(256) void bin_edges(
    const int* __restrict__ dst0, const int* __restrict__ dst1,
    const int* __restrict__ src0, const int* __restrict__ src1,
    int* __restrict__ gcur, int2* __restrict__ binned)
{
    __shared__ int hist[NB], ebase[NB], lcur[NB], gbase[NB], sc[NB];
    __shared__ int2 stage[CH];
    const int bpset = (NE + CH - 1) / CH;
    const int bid = blockIdx.x;
    const int s = bid / bpset, cb = bid - s * bpset;
    const int* dstp = (s < 2) ? (dst0 + (size_t)s * NE) : (dst1 + (size_t)(s - 2) * NE);
    const int* srcp = (s < 2) ? (src0 + (size_t)s * NE) : (src1 + (size_t)(s - 2) * NE);
    const int e0 = cb * CH;
    const int t = threadIdx.x;

    if (t < NB) hist[t] = 0;
    __syncthreads();

    int myd[8], mys[8];
#pragma unroll
    for (int k = 0; k < 8; k++) {
        const int e = e0 + t + k * 256;
        if (e < NE) {
            const int d = dstp[e];
            myd[k] = d;
            mys[k] = srcp[e];
            atomicAdd(&hist[(d * NB) / NN], 1);
        } else myd[k] = -1;
    }
    __syncthreads();
    if (t < NB) sc[t] = hist[t];
    __syncthreads();
    for (int o = 1; o < NB; o <<= 1) {
        int tv = 0;
        if (t < NB && t >= o) tv = sc[t - o];
        __syncthreads();
        if (t < NB) sc[t] += tv;
        __syncthreads();
    }
    if (t < NB) {
        ebase[t] = sc[t] - hist[t];
        lcur[t]  = sc[t] - hist[t];
        gbase[t] = atomicAdd(&gcur[s * NB + t], hist[t]);
    }
    __syncthreads();
#pragma unroll
    for (int k = 0; k < 8; k++) {
        if (myd[k] >= 0) {
            const int b = (myd[k] * NB) / NN;
            const int p = atomicAdd(&lcur[b], 1);
            stage[p] = make_int2(myd[k], mys[k]);
        }
    }
    __syncthreads();
    int2* bset = binned + (size_t)s * NE;
    const int total = ebase[NB - 1] + hist[NB - 1];
    for (int i = t; i < total; i += 256) {
        const int2 v = stage[i];
        const int b = (v.x * NB) / NN;
        bset[gbase[b] + (i - ebase[b])] = v;
    }
}

__global__ __launch_bounds__(256) void build_csr(
    const int* __restrict__ bbase, const int2* __restrict__ binned,
    int* __restrict__ row, int* __restrict__ csr_src)
{
    __shared__ int A[512], B[512], lcur[512];
    const int bid = blockIdx.x;
    const int s = bid >> 7, b = bid & (NB - 1);
    const int nb0 = (b * NN + NB - 1) / NB;
    int nb1 = ((b + 1) * NN + NB - 1) / NB;
    if (nb1 > NN) nb1 = NN;
    const int nloc = nb1 - nb0;
    const int jb = bbase[s * (NB + 1) + b], je = bbase[s * (NB + 1) + b + 1];
    const int t = threadIdx.x;

    A[t] = 0; A[t + 256] = 0;
    __syncthreads();
    const int2* bset = binned + (size_t)s * NE;
    for (int j = jb + t; j < je; j += 256)
        atomicAdd(&A[bset[j].x - nb0], 1);
    __syncthreads();
    const int c0 = A[t], c1 = A[t + 256];
    int* cur = A; int* nxt = B;
    for (int off = 1; off < 512; off <<= 1) {
        nxt[t]       = cur[t]       + ((t >= off)       ? cur[t - off]       : 0);
        nxt[t + 256] = cur[t + 256] + ((t + 256 >= off) ? cur[t + 256 - off] : 0);
        __syncthreads();
        int* tmp = cur; cur = nxt; nxt = tmp;
    }
    if (t < nloc) {
        const int v = jb + cur[t] - c0;
        lcur[t] = v;
        row[s * (NN + 1) + nb0 + t] = v;
    }
    if (t + 256 < nloc) {
        const int v = jb + cur[t + 256] - c1;
        lcur[t + 256] = v;
        row[s * (NN + 1) + nb0 + t + 256] = v;
    }
    __syncthreads();
    int* outp = csr_src + (size_t)s * NE;
    for (int j = jb + t; j < je; j += 256) {
        const int2 v = bset[j];
        const int p = atomicAdd(&lcur[v.x - nb0], 1);
        outp[p] = v.y;
    }
}

__device__ __forceinline__ float elu(float v) { return v > 0.f ? v : expm1f(v); }

// ---------------- fused softmax + aggregate (bf16 gather table) -------------
// Wave per dst node. Fast path (deg<=64): single gather of scores, register
// ex, shfl broadcast. mode 0: outp=elu(agg+b). mode 1: outp=accin+elu(agg+b).
__global__ __launch_bounds__(256) void aggregate_fused(
    const int* __restrict__ row, const int* __restrict__ csr_src,
    const float2* __restrict__ el, const float2* __restrict__ er,
    const ushort* __restrict__ fg, const float* __restrict__ bias,
    const float* __restrict__ accin, float* __restrict__ outp, int mode)
{
    const int wv = (blockIdx.x * 256 + threadIdx.x) >> 6;
    if (wv >= NN) return;
    const int lane = threadIdx.x & 63;
    const int beg = row[wv], end = row[wv + 1];
    const int deg = end - beg;
    const float2 erd = er[wv];

    float2 acc = make_float2(0.f, 0.f);

    if (deg <= 64) {
        int s = -1;
        float ex0 = 0.f, ex1 = 0.f;
        const int j = beg + lane;
        if (lane < deg) {
            s = csr_src[j];
            const float2 els = el[s];
            float e0 = els.x + erd.x, e1 = els.y + erd.y;
            e0 = e0 > 0.f ? e0 : 0.2f * e0;
            e1 = e1 > 0.f ? e1 : 0.2f * e1;
            ex0 = __expf(e0);
            ex1 = __expf(e1);
        }
        float den0 = ex0, den1 = ex1;
        for (int o = 32; o > 0; o >>= 1) {
            den0 += __shfl_xor(den0, o);
            den1 += __shfl_xor(den1, o);
        }
        const float inv0 = 1.0f / den0, inv1 = 1.0f / den1;
        for (int tt = 0; tt < deg; tt++) {
            const int st = __shfl(s, tt);
            const float a0 = __shfl(ex0, tt);
            const float a1 = __shfl(ex1, tt);
            const float aa = (lane < 32) ? a0 * inv0 : a1 * inv1;
            const uint u = *(const uint*)(fg + (size_t)st * DIM + 2 * lane);
            union { uint i; float f; } lo, hi;
            lo.i = u << 16;
            hi.i = u & 0xffff0000u;
            acc.x += lo.f * aa;
            acc.y += hi.f * aa;
        }
    } else {
        // generic two-pass (statistically never hit at Poisson(16))
        float den0 = 0.f, den1 = 0.f;
        for (int c0 = beg; c0 < end; c0 += 64) {
            const int j = c0 + lane;
            if (j < end) {
                const float2 els = el[csr_src[j]];
                float e0 = els.x + erd.x, e1 = els.y + erd.y;
                e0 = e0 > 0.f ? e0 : 0.2f * e0;
                e1 = e1 > 0.f ? e1 : 0.2f * e1;
                den0 += __expf(e0);
                den1 += __expf(e1);
            }
        }
        for (int o = 32; o > 0; o >>= 1) {
            den0 += __shfl_xor(den0, o);
            den1 += __shfl_xor(den1, o);
        }
        const float inv0 = 1.0f / den0, inv1 = 1.0f / den1;
        for (int c0 = beg; c0 < end; c0 += 64) {
            const int j = c0 + lane;
            int s = -1;
            float ex0 = 0.f, ex1 = 0.f;
            if (j < end) {
                s = csr_src[j];
                const float2 els = el[s];
                float e0 = els.x + erd.x, e1 = els.y + erd.y;
                e0 = e0 > 0.f ? e0 : 0.2f * e0;
                e1 = e1 > 0.f ? e1 : 0.2f * e1;
                ex0 = __expf(e0) * inv0;
                ex1 = __expf(e1) * inv1;
            }
            const int cm = min(64, end - c0);
            for (int tt = 0; tt < cm; tt++) {
                const int st = __shfl(s, tt);
                const float a0 = __shfl(ex0, tt);
                const float a1 = __shfl(ex1, tt);
                const float aa = (lane < 32) ? a0 : a1;
                const uint u = *(const uint*)(fg + (size_t)st * DIM + 2 * lane);
                union { uint i; float f; } lo, hi;
                lo.i = u << 16;
                hi.i = u & 0xffff0000u;
                acc.x += lo.f * aa;
                acc.y += hi.f * aa;
            }
        }
    }

    const float b0 = bias[2 * lane], b1 = bias[2 * lane + 1];
    float o0 = elu(acc.x + b0);
    float o1 = elu(acc.y + b1);
    float* op = outp + (size_t)wv * DIM + 2 * lane;
    if (mode) {
        const float2 ap = *(const float2*)(accin + (size_t)wv * DIM + 2 * lane);
        o0 += ap.x; o1 += ap.y;
    }
    op[0] = o0; op[1] = o1;
}

extern "C" void kernel_launch(void* const* d_in, const int* in_sizes, int n_in,
                              void* d_out, int out_size, void* d_ws, size_t ws_size,
                              hipStream_t stream)
{
    const float* x   = (const float*)d_in[0];
    const float* W0  = (const float*)d_in[1];
    const float* al0 = (const float*)d_in[2];
    const float* ar0 = (const float*)d_in[3];
    const float* b0  = (const float*)d_in[4];
    const float* W1  = (const float*)d_in[5];
    const float* al1 = (const float*)d_in[6];
    const float* ar1 = (const float*)d_in[7];
    const float* b1  = (const float*)d_in[8];
    const int* src0 = (const int*)d_in[9];
    const int* dst0 = (const int*)d_in[10];
    const int* src1 = (const int*)d_in[11];
    const int* dst1 = (const int*)d_in[12];
    float* out = (float*)d_out;

    char* w = (char*)d_ws;
    auto alloc = [&](size_t bytes) {
        char* p = w; w += (bytes + 255) & ~(size_t)255; return p;
    };
    ushort* fg     = (ushort*)alloc((size_t)NN * DIM * 2);  // bf16 gather table
    float*  h1     = (float*)alloc((size_t)NN * DIM * 4);
    float*  accbuf = (float*)alloc((size_t)NN * DIM * 4);   // aliased as binned
    float*  el     = (float*)alloc((size_t)NN * 2 * 4);
    float*  er     = (float*)alloc((size_t)NN * 2 * 4);
    int*    row    = (int*)alloc((size_t)4 * (NN + 1) * 4);
    int*    csr    = (int*)alloc((size_t)4 * NE * 4);
    int*    bcount = (int*)alloc((size_t)4 * NB * 4);
    int*    bbase  = (int*)alloc((size_t)4 * (NB + 1) * 4);
    int*    gcur   = (int*)alloc((size_t)4 * NB * 4);
    int2*   binned = (int2*)accbuf;  // 4*NE*8 = 25.6MB == accbuf; consumed by
                                     // build_csr before first aggregate writes accbuf

    // ---- CSR build ----
    hipMemsetAsync(bcount, 0, (size_t)4 * NB * 4, stream);
    {
        const int bpset = (NE + CH - 1) / CH;
        bucket_hist<<<4 * bpset, 256, 0, stream>>>(dst0, dst1, bcount);
        scan_buckets<<<1, 64, 0, stream>>>(bcount, bbase, gcur, row);
        bin_edges<<<4 * bpset, 256, 0, stream>>>(dst0, dst1, src0, src1, gcur, binned);
    }
    build_csr<<<4 * NB, 256, 0, stream>>>(bbase, binned, row, csr);

    for (int L = 0; L < 2; L++) {
        const float* hin = L ? h1 : x;
        const float* W   = L ? W1 : W0;
        const float* al  = L ? al1 : al0;
        const float* ar  = L ? ar1 : ar0;
        const float* b   = L ? b1 : b0;
        for (int r = 0; r < 2; r++) {
            const int es = L * 2 + r;
            gemm128<<<(NN + 63) / 64, 256, 0, stream>>>(
                hin, W + (size_t)r * DIM * DIM, al + r * DIM, ar + r * DIM,
                fg, el, er, NN);
            aggregate_fused<<<(NN * 64 + 255) / 256, 256, 0, stream>>>(
                row + es * (NN + 1), csr + (size_t)es * NE,
                (const float2*)el, (const float2*)er, fg, b + r * DIM,
                accbuf, (r == 0) ? accbuf : (L ? out : h1), r);
        }
    }
}

// Round 8
// 426.570 us; speedup vs baseline: 7.8038x; 1.2890x over previous
//
#include <hip/hip_runtime.h>

#define NN 50000
#define NE 800000
#define DIM 128
#define NB 128          // dst buckets for binned CSR build
#define CH 4096         // edges per binning block

typedef unsigned int uint;
typedef unsigned short ushort;

__device__ __forceinline__ ushort f2bf(float f) {
    union { float f; uint i; } c; c.f = f;
    const uint r = (c.i + 0x7fffu + ((c.i >> 16) & 1u)) >> 16;
    return (ushort)r;
}

// ---------------- dense GEMM: fg(bf16) = h @ W; fused el/er epilogue --------
__global__ __launch_bounds__(256) void gemm128(
    const float* __restrict__ h, const float* __restrict__ W,
    const float* __restrict__ al, const float* __restrict__ ar,
    ushort* __restrict__ fg, float* __restrict__ el, float* __restrict__ er,
    int n)
{
    __shared__ float Ws[32][132];
    __shared__ float hsm[64][33];
    __shared__ float pel[64][17];
    __shared__ float per2[64][17];
    const int tid = threadIdx.x;
    const int rg = tid >> 4;
    const int cg = tid & 15;
    const long row0 = (long)blockIdx.x * 64;

    float alv[8], arv[8];
#pragma unroll
    for (int j = 0; j < 8; j++) {
        alv[j] = al[cg * 8 + j];
        arv[j] = ar[cg * 8 + j];
    }

    float acc[4][8];
#pragma unroll
    for (int i = 0; i < 4; i++)
#pragma unroll
        for (int j = 0; j < 8; j++) acc[i][j] = 0.0f;

    for (int k0 = 0; k0 < 128; k0 += 32) {
        __syncthreads();
        {
            const float4* Wg = (const float4*)(W + (size_t)k0 * 128);
#pragma unroll
            for (int i = 0; i < 4; i++) {
                const int idx = tid + 256 * i;
                const int r = idx >> 5;
                const int c = idx & 31;
                const float4 v = Wg[idx];
                Ws[r][c * 4 + 0] = v.x; Ws[r][c * 4 + 1] = v.y;
                Ws[r][c * 4 + 2] = v.z; Ws[r][c * 4 + 3] = v.w;
            }
        }
        {
            const int r = tid >> 2;
            const int c = tid & 3;
            const long nrow = row0 + r;
            float4 a = make_float4(0.f, 0.f, 0.f, 0.f), b = a;
            if (nrow < n) {
                const float4* hp = (const float4*)(h + nrow * DIM + k0 + c * 8);
                a = hp[0]; b = hp[1];
            }
            float* dp = &hsm[r][c * 8];
            dp[0] = a.x; dp[1] = a.y; dp[2] = a.z; dp[3] = a.w;
            dp[4] = b.x; dp[5] = b.y; dp[6] = b.z; dp[7] = b.w;
        }
        __syncthreads();
#pragma unroll
        for (int k = 0; k < 32; k++) {
            const float hv0 = hsm[rg * 4 + 0][k];
            const float hv1 = hsm[rg * 4 + 1][k];
            const float hv2 = hsm[rg * 4 + 2][k];
            const float hv3 = hsm[rg * 4 + 3][k];
            const float* wr = &Ws[k][cg * 8];
#pragma unroll
            for (int j = 0; j < 8; j++) {
                const float wv = wr[j];
                acc[0][j] += hv0 * wv;
                acc[1][j] += hv1 * wv;
                acc[2][j] += hv2 * wv;
                acc[3][j] += hv3 * wv;
            }
        }
    }

#pragma unroll
    for (int i = 0; i < 4; i++) {
        const int lrow = rg * 4 + i;
        const long nr = row0 + lrow;
        float sl = 0.f, sr = 0.f;
#pragma unroll
        for (int j = 0; j < 8; j++) {
            sl += acc[i][j] * alv[j];
            sr += acc[i][j] * arv[j];
        }
        pel[lrow][cg] = sl;
        per2[lrow][cg] = sr;
        if (nr < n) {
            ushort tmp[8];
#pragma unroll
            for (int j = 0; j < 8; j++) tmp[j] = f2bf(acc[i][j]);
            *(uint4*)(fg + (size_t)nr * DIM + cg * 8) = *(const uint4*)tmp;
        }
    }
    __syncthreads();
    if (tid < 128) {
        const int lrow = tid >> 1, head = tid & 1;
        const long nr = row0 + lrow;
        if (nr < n) {
            float sl = 0.f, sr = 0.f;
#pragma unroll
            for (int k = 0; k < 8; k++) {
                sl += pel[lrow][head * 8 + k];
                sr += per2[lrow][head * 8 + k];
            }
            el[nr * 2 + head] = sl;
            er[nr * 2 + head] = sr;
        }
    }
}

// ---------------- CSR build ----------------
__global__ __launch_bounds__(256) void bucket_hist(
    const int* __restrict__ dst0, const int* __restrict__ dst1,
    int* __restrict__ bcount)
{
    __shared__ int hist[NB];
    const int bpset = (NE + CH - 1) / CH;
    const int bid = blockIdx.x;
    const int s = bid / bpset, cb = bid - s * bpset;
    const int* dstp = (s < 2) ? (dst0 + (size_t)s * NE) : (dst1 + (size_t)(s - 2) * NE);
    const int e0 = cb * CH;
    const int t = threadIdx.x;
    if (t < NB) hist[t] = 0;
    __syncthreads();
#pragma unroll
    for (int k = 0; k < 16; k++) {
        const int e = e0 + t + k * 256;
        if (e < NE) atomicAdd(&hist[(dstp[e] * NB) / NN], 1);
    }
    __syncthreads();
    if (t < NB && hist[t]) atomicAdd(&bcount[s * NB + t], hist[t]);
}

__global__ __launch_bounds__(64) void scan_buckets(
    const int* __restrict__ bcount, int* __restrict__ bbase,
    int* __restrict__ gcur, int* __restrict__ row)
{
    const int s = threadIdx.x;
    if (s < 4) {
        int acc = 0;
        for (int b = 0; b < NB; b++) {
            bbase[s * (NB + 1) + b] = acc;
            gcur[s * NB + b] = acc;
            acc += bcount[s * NB + b];
        }
        bbase[s * (NB + 1) + NB] = acc;
        row[s * (NN + 1) + NN] = NE;
    }
}

// Pass A: bin edges by dst bucket; payload packed (dst<<16)|src (both <65536).
__global__ __launch_bounds__(256) void bin_edges(
    const int* __restrict__ dst0, const int* __restrict__ dst1,
    const int* __restrict__ src0, const int* __restrict__ src1,
    int* __restrict__ gcur, uint* __restrict__ binned)
{
    __shared__ int hist[NB], ebase[NB], lcur[NB], gbase[NB], sc[NB];
    __shared__ uint stage[CH];
    const int bpset = (NE + CH - 1) / CH;
    const int bid = blockIdx.x;
    const int s = bid / bpset, cb = bid - s * bpset;
    const int* dstp = (s < 2) ? (dst0 + (size_t)s * NE) : (dst1 + (size_t)(s - 2) * NE);
    const int* srcp = (s < 2) ? (src0 + (size_t)s * NE) : (src1 + (size_t)(s - 2) * NE);
    const int e0 = cb * CH;
    const int t = threadIdx.x;

    if (t < NB) hist[t] = 0;
    __syncthreads();

    int myd[16], mys[16];
#pragma unroll
    for (int k = 0; k < 16; k++) {
        const int e = e0 + t + k * 256;
        if (e < NE) {
            const int d = dstp[e];
            myd[k] = d;
            mys[k] = srcp[e];
            atomicAdd(&hist[(d * NB) / NN], 1);
        } else myd[k] = -1;
    }
    __syncthreads();
    if (t < NB) sc[t] = hist[t];
    __syncthreads();
    for (int o = 1; o < NB; o <<= 1) {
        int tv = 0;
        if (t < NB && t >= o) tv = sc[t - o];
        __syncthreads();
        if (t < NB) sc[t] += tv;
        __syncthreads();
    }
    if (t < NB) {
        ebase[t] = sc[t] - hist[t];
        lcur[t]  = sc[t] - hist[t];
        gbase[t] = atomicAdd(&gcur[s * NB + t], hist[t]);
    }
    __syncthreads();
#pragma unroll
    for (int k = 0; k < 16; k++) {
        if (myd[k] >= 0) {
            const int b = (myd[k] * NB) / NN;
            const int p = atomicAdd(&lcur[b], 1);
            stage[p] = ((uint)myd[k] << 16) | (uint)mys[k];
        }
    }
    __syncthreads();
    uint* bset = binned + (size_t)s * NE;
    const int total = ebase[NB - 1] + hist[NB - 1];
    for (int i = t; i < total; i += 256) {
        const uint v = stage[i];
        const int b = ((int)(v >> 16) * NB) / NN;
        bset[gbase[b] + (i - ebase[b])] = v;
    }
}

// Pass B: per (set,bucket): LDS degree count + scan -> row[] + ushort csr.
__global__ __launch_bounds__(256) void build_csr(
    const int* __restrict__ bbase, const uint* __restrict__ binned,
    int* __restrict__ row, ushort* __restrict__ csr_src)
{
    __shared__ int A[512], B[512], lcur[512];
    const int bid = blockIdx.x;
    const int s = bid >> 7, b = bid & (NB - 1);
    const int nb0 = (b * NN + NB - 1) / NB;
    int nb1 = ((b + 1) * NN + NB - 1) / NB;
    if (nb1 > NN) nb1 = NN;
    const int nloc = nb1 - nb0;
    const int jb = bbase[s * (NB + 1) + b], je = bbase[s * (NB + 1) + b + 1];
    const int t = threadIdx.x;

    A[t] = 0; A[t + 256] = 0;
    __syncthreads();
    const uint* bset = binned + (size_t)s * NE;
    for (int j = jb + t; j < je; j += 256)
        atomicAdd(&A[(int)(bset[j] >> 16) - nb0], 1);
    __syncthreads();
    const int c0 = A[t], c1 = A[t + 256];
    int* cur = A; int* nxt = B;
    for (int off = 1; off < 512; off <<= 1) {
        nxt[t]       = cur[t]       + ((t >= off)       ? cur[t - off]       : 0);
        nxt[t + 256] = cur[t + 256] + ((t + 256 >= off) ? cur[t + 256 - off] : 0);
        __syncthreads();
        int* tmp = cur; cur = nxt; nxt = tmp;
    }
    if (t < nloc) {
        const int v = jb + cur[t] - c0;
        lcur[t] = v;
        row[s * (NN + 1) + nb0 + t] = v;
    }
    if (t + 256 < nloc) {
        const int v = jb + cur[t + 256] - c1;
        lcur[t + 256] = v;
        row[s * (NN + 1) + nb0 + t + 256] = v;
    }
    __syncthreads();
    ushort* outp = csr_src + (size_t)s * NE;
    for (int j = jb + t; j < je; j += 256) {
        const uint v = bset[j];
        const int p = atomicAdd(&lcur[(int)(v >> 16) - nb0], 1);
        outp[p] = (ushort)(v & 0xffffu);
    }
}

__device__ __forceinline__ float elu(float v) { return v > 0.f ? v : expm1f(v); }
__device__ __forceinline__ float2 bfpair(uint u) {
    union { uint i; float f; } lo, hi;
    lo.i = u << 16;
    hi.i = u & 0xffff0000u;
    return make_float2(lo.f, hi.f);
}

// ---------------- dual-relation fused softmax + aggregate -------------------
// Wave per dst node; rel 0 then rel 1; out = elu(agg0+b0) + elu(agg1+b1).
// Fast path deg<=64: weights+offsets staged per-wave in LDS, gather unroll x4.
__global__ __launch_bounds__(256) void aggregate_dual(
    const int* __restrict__ row0, const ushort* __restrict__ csr0,
    const int* __restrict__ row1, const ushort* __restrict__ csr1,
    const float2* __restrict__ el0, const float2* __restrict__ er0,
    const float2* __restrict__ el1, const float2* __restrict__ er1,
    const ushort* __restrict__ fg0, const ushort* __restrict__ fg1,
    const float* __restrict__ bias0, const float* __restrict__ bias1,
    float* __restrict__ outp)
{
    __shared__ uint soff[4][64];
    __shared__ float wts[4][2][64];
    const int wv = (blockIdx.x * 256 + threadIdx.x) >> 6;
    if (wv >= NN) return;
    const int lane = threadIdx.x & 63;
    const int wid = threadIdx.x >> 6;

    const int* rows[2] = {row0, row1};
    const ushort* csrs[2] = {csr0, csr1};
    const float2* els[2] = {el0, el1};
    const float2* ers[2] = {er0, er1};
    const ushort* fgs[2] = {fg0, fg1};
    const float* biases[2] = {bias0, bias1};

    float oacc0 = 0.f, oacc1 = 0.f;

#pragma unroll
    for (int rel = 0; rel < 2; rel++) {
        const int beg = rows[rel][wv], end = rows[rel][wv + 1];
        const int deg = end - beg;
        const float2 erd = ers[rel][wv];
        float2 acc = make_float2(0.f, 0.f);

        if (deg <= 64) {
            uint sof = 0;
            float ex0 = 0.f, ex1 = 0.f;
            if (lane < deg) {
                const int s = csrs[rel][beg + lane];
                const float2 e = els[rel][s];
                float e0 = e.x + erd.x, e1 = e.y + erd.y;
                e0 = e0 > 0.f ? e0 : 0.2f * e0;
                e1 = e1 > 0.f ? e1 : 0.2f * e1;
                ex0 = __expf(e0);
                ex1 = __expf(e1);
                sof = (uint)s << 8;   // byte offset of bf16 row (256 B)
            }
            float den0 = ex0, den1 = ex1;
            for (int o = 32; o > 0; o >>= 1) {
                den0 += __shfl_xor(den0, o);
                den1 += __shfl_xor(den1, o);
            }
            const float inv0 = 1.0f / den0, inv1 = 1.0f / den1;
            soff[wid][lane] = sof;
            wts[wid][0][lane] = ex0 * inv0;
            wts[wid][1][lane] = ex1 * inv1;
            const char* fgb = (const char*)fgs[rel] + lane * 4;
            const float* wrow = wts[wid][lane >> 5];
            const uint* sorow = soff[wid];
            int tt = 0;
            for (; tt + 4 <= deg; tt += 4) {
                const uint o0 = sorow[tt],     o1 = sorow[tt + 1];
                const uint o2 = sorow[tt + 2], o3 = sorow[tt + 3];
                const float w0 = wrow[tt],     w1 = wrow[tt + 1];
                const float w2 = wrow[tt + 2], w3 = wrow[tt + 3];
                const uint u0 = *(const uint*)(fgb + o0);
                const uint u1 = *(const uint*)(fgb + o1);
                const uint u2 = *(const uint*)(fgb + o2);
                const uint u3 = *(const uint*)(fgb + o3);
                const float2 f0 = bfpair(u0), f1 = bfpair(u1);
                const float2 f2 = bfpair(u2), f3 = bfpair(u3);
                acc.x += f0.x * w0 + f1.x * w1 + f2.x * w2 + f3.x * w3;
                acc.y += f0.y * w0 + f1.y * w1 + f2.y * w2 + f3.y * w3;
            }
            for (; tt < deg; tt++) {
                const uint o0 = sorow[tt];
                const float w0 = wrow[tt];
                const float2 f0 = bfpair(*(const uint*)(fgb + o0));
                acc.x += f0.x * w0;
                acc.y += f0.y * w0;
            }
        } else {
            // generic two-pass (statistically never hit at Poisson(16))
            float den0 = 0.f, den1 = 0.f;
            for (int c0 = beg; c0 < end; c0 += 64) {
                const int j = c0 + lane;
                if (j < end) {
                    const float2 e = els[rel][csrs[rel][j]];
                    float e0 = e.x + erd.x, e1 = e.y + erd.y;
                    e0 = e0 > 0.f ? e0 : 0.2f * e0;
                    e1 = e1 > 0.f ? e1 : 0.2f * e1;
                    den0 += __expf(e0);
                    den1 += __expf(e1);
                }
            }
            for (int o = 32; o > 0; o >>= 1) {
                den0 += __shfl_xor(den0, o);
                den1 += __shfl_xor(den1, o);
            }
            const float inv0 = 1.0f / den0, inv1 = 1.0f / den1;
            for (int c0 = beg; c0 < end; c0 += 64) {
                const int j = c0 + lane;
                int s = -1;
                float ex0 = 0.f, ex1 = 0.f;
                if (j < end) {
                    s = csrs[rel][j];
                    const float2 e = els[rel][s];
                    float e0 = e.x + erd.x, e1 = e.y + erd.y;
                    e0 = e0 > 0.f ? e0 : 0.2f * e0;
                    e1 = e1 > 0.f ? e1 : 0.2f * e1;
                    ex0 = __expf(e0) * inv0;
                    ex1 = __expf(e1) * inv1;
                }
                const int cm = min(64, end - c0);
                for (int tt = 0; tt < cm; tt++) {
                    const int st = __shfl(s, tt);
                    const float a0 = __shfl(ex0, tt);
                    const float a1 = __shfl(ex1, tt);
                    const float aa = (lane < 32) ? a0 : a1;
                    const float2 fv = bfpair(
                        *(const uint*)((const char*)fgs[rel] + ((size_t)st << 8) + lane * 4));
                    acc.x += fv.x * aa;
                    acc.y += fv.y * aa;
                }
            }
        }

        const float b0 = biases[rel][2 * lane], b1 = biases[rel][2 * lane + 1];
        oacc0 += elu(acc.x + b0);
        oacc1 += elu(acc.y + b1);
    }

    float* op = outp + (size_t)wv * DIM + 2 * lane;
    op[0] = oacc0; op[1] = oacc1;
}

extern "C" void kernel_launch(void* const* d_in, const int* in_sizes, int n_in,
                              void* d_out, int out_size, void* d_ws, size_t ws_size,
                              hipStream_t stream)
{
    const float* x   = (const float*)d_in[0];
    const float* W0  = (const float*)d_in[1];
    const float* al0 = (const float*)d_in[2];
    const float* ar0 = (const float*)d_in[3];
    const float* b0  = (const float*)d_in[4];
    const float* W1  = (const float*)d_in[5];
    const float* al1 = (const float*)d_in[6];
    const float* ar1 = (const float*)d_in[7];
    const float* b1  = (const float*)d_in[8];
    const int* src0 = (const int*)d_in[9];
    const int* dst0 = (const int*)d_in[10];
    const int* src1 = (const int*)d_in[11];
    const int* dst1 = (const int*)d_in[12];
    float* out = (float*)d_out;

    char* w = (char*)d_ws;
    auto alloc = [&](size_t bytes) {
        char* p = w; w += (bytes + 255) & ~(size_t)255; return p;
    };
    ushort* fg0    = (ushort*)alloc((size_t)NN * DIM * 2);
    ushort* fg1    = (ushort*)alloc((size_t)NN * DIM * 2);
    float*  h1     = (float*)alloc((size_t)NN * DIM * 4);
    float*  elb    = (float*)alloc((size_t)4 * NN * 2 * 4);  // el0,er0,el1,er1
    int*    row    = (int*)alloc((size_t)4 * (NN + 1) * 4);
    ushort* csr    = (ushort*)alloc((size_t)4 * NE * 2);
    uint*   binned = (uint*)alloc((size_t)4 * NE * 4);
    int*    bcount = (int*)alloc((size_t)4 * NB * 4);
    int*    bbase  = (int*)alloc((size_t)4 * (NB + 1) * 4);
    int*    gcur   = (int*)alloc((size_t)4 * NB * 4);
    float* el0p = elb;
    float* er0p = elb + (size_t)NN * 2;
    float* el1p = elb + (size_t)NN * 4;
    float* er1p = elb + (size_t)NN * 6;

    // ---- CSR build ----
    hipMemsetAsync(bcount, 0, (size_t)4 * NB * 4, stream);
    {
        const int bpset = (NE + CH - 1) / CH;
        bucket_hist<<<4 * bpset, 256, 0, stream>>>(dst0, dst1, bcount);
        scan_buckets<<<1, 64, 0, stream>>>(bcount, bbase, gcur, row);
        bin_edges<<<4 * bpset, 256, 0, stream>>>(dst0, dst1, src0, src1, gcur, binned);
    }
    build_csr<<<4 * NB, 256, 0, stream>>>(bbase, binned, row, csr);

    for (int L = 0; L < 2; L++) {
        const float* hin = L ? h1 : x;
        const float* W   = L ? W1 : W0;
        const float* al  = L ? al1 : al0;
        const float* ar  = L ? ar1 : ar0;
        const float* b   = L ? b1 : b0;
        gemm128<<<(NN + 63) / 64, 256, 0, stream>>>(
            hin, W, al, ar, fg0, el0p, er0p, NN);
        gemm128<<<(NN + 63) / 64, 256, 0, stream>>>(
            hin, W + (size_t)DIM * DIM, al + DIM, ar + DIM, fg1, el1p, er1p, NN);
        const int es0 = L * 2, es1 = L * 2 + 1;
        aggregate_dual<<<(NN * 64 + 255) / 256, 256, 0, stream>>>(
            row + es0 * (NN + 1), csr + (size_t)es0 * NE,
            row + es1 * (NN + 1), csr + (size_t)es1 * NE,
            (const float2*)el0p, (const float2*)er0p,
            (const float2*)el1p, (const float2*)er1p,
            fg0, fg1, b, b + DIM, L ? out : h1);
    }
}

// Round 9
// 396.623 us; speedup vs baseline: 8.3930x; 1.0755x over previous
//
#include <hip/hip_runtime.h>

#define NN 50000
#define NE 800000
#define DIM 128
#define NB 128          // dst buckets for binned CSR build
#define CH 4096         // edges per binning block

typedef unsigned int uint;
typedef unsigned short ushort;
typedef __attribute__((ext_vector_type(8))) short v8s;
typedef __attribute__((ext_vector_type(4))) float v4f;

__device__ __forceinline__ ushort f2bf(float f) {
    union { float f; uint i; } c; c.f = f;
    const uint r = (c.i + 0x7fffu + ((c.i >> 16) & 1u)) >> 16;
    return (ushort)r;
}

// ---------------- one-time converts ----------------
// x (f32) -> xbf (bf16). 8 elems/thread.
__global__ __launch_bounds__(256) void convert_x(
    const float* __restrict__ x, ushort* __restrict__ xbf, int total8)
{
    const int t = blockIdx.x * 256 + threadIdx.x;
    if (t >= total8) return;
    const float4* xp = (const float4*)(x + (size_t)t * 8);
    const float4 a = xp[0], b = xp[1];
    ushort tmp[8] = { f2bf(a.x), f2bf(a.y), f2bf(a.z), f2bf(a.w),
                      f2bf(b.x), f2bf(b.y), f2bf(b.z), f2bf(b.w) };
    *(uint4*)(xbf + (size_t)t * 8) = *(const uint4*)tmp;
}

// WT[m][n][k] = bf16(W[m][k][n]); m: 0,1 from W0, 2,3 from W1.
__global__ __launch_bounds__(256) void conv_wt(
    const float* __restrict__ W0, const float* __restrict__ W1,
    ushort* __restrict__ WT)
{
    const int t = blockIdx.x * 256 + threadIdx.x;   // 16384 threads x 4 elems
#pragma unroll
    for (int i = 0; i < 4; i++) {
        const int o = t * 4 + i;                    // 0 .. 65535
        const int m = o >> 14, rem = o & 16383;
        const int nrow = rem >> 7, k = rem & 127;
        const float* src = (m < 2) ? (W0 + (size_t)m * 16384)
                                   : (W1 + (size_t)(m - 2) * 16384);
        WT[o] = f2bf(src[k * 128 + nrow]);
    }
}

// ---------------- MFMA GEMM: fg(bf16) = hbf @ W (WT pre-transposed) ---------
// Block 256 = 4 waves; wave w: rows [b*64+16w, +16), all 128 cols.
// No LDS, no barriers. Fused el/er epilogue.
__global__ __launch_bounds__(256) void gemm_mfma(
    const ushort* __restrict__ hbf, const ushort* __restrict__ WT,
    const float* __restrict__ al, const float* __restrict__ ar,
    ushort* __restrict__ fg, float* __restrict__ el, float* __restrict__ er,
    int n)
{
    const int tid = threadIdx.x;
    const int w = tid >> 6, lane = tid & 63;
    const int quad = lane >> 4, l16 = lane & 15;
    const int row0 = blockIdx.x * 64 + w * 16;

    v4f acc[8];
#pragma unroll
    for (int nt = 0; nt < 8; nt++) acc[nt] = (v4f)0.0f;

    int arow = row0 + l16;
    if (arow >= n) arow = n - 1;           // clamp: garbage rows never stored
    const ushort* ap = hbf + (size_t)arow * DIM + quad * 8;
    const ushort* bp = WT + (size_t)l16 * DIM + quad * 8;

#pragma unroll
    for (int kt = 0; kt < 4; kt++) {
        const v8s a = *(const v8s*)(ap + kt * 32);
        v8s b[8];
#pragma unroll
        for (int nt = 0; nt < 8; nt++)
            b[nt] = *(const v8s*)(bp + (size_t)nt * 16 * DIM + kt * 32);
#pragma unroll
        for (int nt = 0; nt < 8; nt++)
            acc[nt] = __builtin_amdgcn_mfma_f32_16x16x32_bf16(a, b[nt], acc[nt], 0, 0, 0);
    }

    // epilogue: store bf16 f, reduce el/er per row (quad holds rows quad*4+r)
    float pel[4][2], per2[4][2];
#pragma unroll
    for (int r = 0; r < 4; r++)
        pel[r][0] = pel[r][1] = per2[r][0] = per2[r][1] = 0.f;

#pragma unroll
    for (int nt = 0; nt < 8; nt++) {
        const int col = nt * 16 + l16;
        const float av = al[col], rv = ar[col];
        const int head = nt >> 2;
#pragma unroll
        for (int r = 0; r < 4; r++) {
            const float v = acc[nt][r];
            const int row = row0 + quad * 4 + r;
            if (row < n) fg[(size_t)row * DIM + col] = f2bf(v);
            pel[r][head] += v * av;
            per2[r][head] += v * rv;
        }
    }
#pragma unroll
    for (int o = 1; o < 16; o <<= 1) {
#pragma unroll
        for (int r = 0; r < 4; r++) {
#pragma unroll
            for (int h = 0; h < 2; h++) {
                pel[r][h] += __shfl_xor(pel[r][h], o);
                per2[r][h] += __shfl_xor(per2[r][h], o);
            }
        }
    }
    if (l16 == 0) {
#pragma unroll
        for (int r = 0; r < 4; r++) {
            const int row = row0 + quad * 4 + r;
            if (row < n) {
#pragma unroll
                for (int h = 0; h < 2; h++) {
                    el[row * 2 + h] = pel[r][h];
                    er[row * 2 + h] = per2[r][h];
                }
            }
        }
    }
}

// ---------------- CSR build ----------------
__global__ __launch_bounds__(256) void bucket_hist(
    const int* __restrict__ dst0, const int* __restrict__ dst1,
    int* __restrict__ bcount)
{
    __shared__ int hist[NB];
    const int bpset = (NE + CH - 1) / CH;
    const int bid = blockIdx.x;
    const int s = bid / bpset, cb = bid - s * bpset;
    const int* dstp = (s < 2) ? (dst0 + (size_t)s * NE) : (dst1 + (size_t)(s - 2) * NE);
    const int e0 = cb * CH;
    const int t = threadIdx.x;
    if (t < NB) hist[t] = 0;
    __syncthreads();
#pragma unroll
    for (int k = 0; k < 16; k++) {
        const int e = e0 + t + k * 256;
        if (e < NE) atomicAdd(&hist[(dstp[e] * NB) / NN], 1);
    }
    __syncthreads();
    if (t < NB && hist[t]) atomicAdd(&bcount[s * NB + t], hist[t]);
}

__global__ __launch_bounds__(64) void scan_buckets(
    const int* __restrict__ bcount, int* __restrict__ bbase,
    int* __restrict__ gcur, int* __restrict__ row)
{
    const int s = threadIdx.x;
    if (s < 4) {
        int acc = 0;
        for (int b = 0; b < NB; b++) {
            bbase[s * (NB + 1) + b] = acc;
            gcur[s * NB + b] = acc;
            acc += bcount[s * NB + b];
        }
        bbase[s * (NB + 1) + NB] = acc;
        row[s * (NN + 1) + NN] = NE;
    }
}

__global__ __launch_bounds__(256) void bin_edges(
    const int* __restrict__ dst0, const int* __restrict__ dst1,
    const int* __restrict__ src0, const int* __restrict__ src1,
    int* __restrict__ gcur, uint* __restrict__ binned)
{
    __shared__ int hist[NB], ebase[NB], lcur[NB], gbase[NB], sc[NB];
    __shared__ uint stage[CH];
    const int bpset = (NE + CH - 1) / CH;
    const int bid = blockIdx.x;
    const int s = bid / bpset, cb = bid - s * bpset;
    const int* dstp = (s < 2) ? (dst0 + (size_t)s * NE) : (dst1 + (size_t)(s - 2) * NE);
    const int* srcp = (s < 2) ? (src0 + (size_t)s * NE) : (src1 + (size_t)(s - 2) * NE);
    const int e0 = cb * CH;
    const int t = threadIdx.x;

    if (t < NB) hist[t] = 0;
    __syncthreads();

    int myd[16], mys[16];
#pragma unroll
    for (int k = 0; k < 16; k++) {
        const int e = e0 + t + k * 256;
        if (e < NE) {
            const int d = dstp[e];
            myd[k] = d;
            mys[k] = srcp[e];
            atomicAdd(&hist[(d * NB) / NN], 1);
        } else myd[k] = -1;
    }
    __syncthreads();
    if (t < NB) sc[t] = hist[t];
    __syncthreads();
    for (int o = 1; o < NB; o <<= 1) {
        int tv = 0;
        if (t < NB && t >= o) tv = sc[t - o];
        __syncthreads();
        if (t < NB) sc[t] += tv;
        __syncthreads();
    }
    if (t < NB) {
        ebase[t] = sc[t] - hist[t];
        lcur[t]  = sc[t] - hist[t];
        gbase[t] = atomicAdd(&gcur[s * NB + t], hist[t]);
    }
    __syncthreads();
#pragma unroll
    for (int k = 0; k < 16; k++) {
        if (myd[k] >= 0) {
            const int b = (myd[k] * NB) / NN;
            const int p = atomicAdd(&lcur[b], 1);
            stage[p] = ((uint)myd[k] << 16) | (uint)mys[k];
        }
    }
    __syncthreads();
    uint* bset = binned + (size_t)s * NE;
    const int total = ebase[NB - 1] + hist[NB - 1];
    for (int i = t; i < total; i += 256) {
        const uint v = stage[i];
        const int b = ((int)(v >> 16) * NB) / NN;
        bset[gbase[b] + (i - ebase[b])] = v;
    }
}

__global__ __launch_bounds__(256) void build_csr(
    const int* __restrict__ bbase, const uint* __restrict__ binned,
    int* __restrict__ row, ushort* __restrict__ csr_src)
{
    __shared__ int A[512], B[512], lcur[512];
    const int bid = blockIdx.x;
    const int s = bid >> 7, b = bid & (NB - 1);
    const int nb0 = (b * NN + NB - 1) / NB;
    int nb1 = ((b + 1) * NN + NB - 1) / NB;
    if (nb1 > NN) nb1 = NN;
    const int nloc = nb1 - nb0;
    const int jb = bbase[s * (NB + 1) + b], je = bbase[s * (NB + 1) + b + 1];
    const int t = threadIdx.x;

    A[t] = 0; A[t + 256] = 0;
    __syncthreads();
    const uint* bset = binned + (size_t)s * NE;
    for (int j = jb + t; j < je; j += 256)
        atomicAdd(&A[(int)(bset[j] >> 16) - nb0], 1);
    __syncthreads();
    const int c0 = A[t], c1 = A[t + 256];
    int* cur = A; int* nxt = B;
    for (int off = 1; off < 512; off <<= 1) {
        nxt[t]       = cur[t]       + ((t >= off)       ? cur[t - off]       : 0);
        nxt[t + 256] = cur[t + 256] + ((t + 256 >= off) ? cur[t + 256 - off] : 0);
        __syncthreads();
        int* tmp = cur; cur = nxt; nxt = tmp;
    }
    if (t < nloc) {
        const int v = jb + cur[t] - c0;
        lcur[t] = v;
        row[s * (NN + 1) + nb0 + t] = v;
    }
    if (t + 256 < nloc) {
        const int v = jb + cur[t + 256] - c1;
        lcur[t + 256] = v;
        row[s * (NN + 1) + nb0 + t + 256] = v;
    }
    __syncthreads();
    ushort* outp = csr_src + (size_t)s * NE;
    for (int j = jb + t; j < je; j += 256) {
        const uint v = bset[j];
        const int p = atomicAdd(&lcur[(int)(v >> 16) - nb0], 1);
        outp[p] = (ushort)(v & 0xffffu);
    }
}

__device__ __forceinline__ float elu(float v) { return v > 0.f ? v : expm1f(v); }
__device__ __forceinline__ float2 bfpair(uint u) {
    union { uint i; float f; } lo, hi;
    lo.i = u << 16;
    hi.i = u & 0xffff0000u;
    return make_float2(lo.f, hi.f);
}

// ---------------- dual-relation fused softmax + aggregate -------------------
// Wave per dst node; rel 0 then rel 1; out = elu(agg0+b0) + elu(agg1+b1).
// obf!=0: write bf16 (layer-0 hidden); else f32.
__global__ __launch_bounds__(256) void aggregate_dual(
    const int* __restrict__ row0, const ushort* __restrict__ csr0,
    const int* __restrict__ row1, const ushort* __restrict__ csr1,
    const float2* __restrict__ el0, const float2* __restrict__ er0,
    const float2* __restrict__ el1, const float2* __restrict__ er1,
    const ushort* __restrict__ fg0, const ushort* __restrict__ fg1,
    const float* __restrict__ bias0, const float* __restrict__ bias1,
    float* __restrict__ outf, ushort* __restrict__ outbf, int obf)
{
    __shared__ uint soff[4][64];
    __shared__ float wts[4][2][64];
    const int wv = (blockIdx.x * 256 + threadIdx.x) >> 6;
    if (wv >= NN) return;
    const int lane = threadIdx.x & 63;
    const int wid = threadIdx.x >> 6;

    const int* rows[2] = {row0, row1};
    const ushort* csrs[2] = {csr0, csr1};
    const float2* els[2] = {el0, el1};
    const float2* ers[2] = {er0, er1};
    const ushort* fgs[2] = {fg0, fg1};
    const float* biases[2] = {bias0, bias1};

    float oacc0 = 0.f, oacc1 = 0.f;

#pragma unroll
    for (int rel = 0; rel < 2; rel++) {
        const int beg = rows[rel][wv], end = rows[rel][wv + 1];
        const int deg = end - beg;
        const float2 erd = ers[rel][wv];
        float2 acc = make_float2(0.f, 0.f);

        if (deg <= 64) {
            uint sof = 0;
            float ex0 = 0.f, ex1 = 0.f;
            if (lane < deg) {
                const int s = csrs[rel][beg + lane];
                const float2 e = els[rel][s];
                float e0 = e.x + erd.x, e1 = e.y + erd.y;
                e0 = e0 > 0.f ? e0 : 0.2f * e0;
                e1 = e1 > 0.f ? e1 : 0.2f * e1;
                ex0 = __expf(e0);
                ex1 = __expf(e1);
                sof = (uint)s << 8;
            }
            float den0 = ex0, den1 = ex1;
            for (int o = 32; o > 0; o >>= 1) {
                den0 += __shfl_xor(den0, o);
                den1 += __shfl_xor(den1, o);
            }
            const float inv0 = 1.0f / den0, inv1 = 1.0f / den1;
            soff[wid][lane] = sof;
            wts[wid][0][lane] = ex0 * inv0;
            wts[wid][1][lane] = ex1 * inv1;
            const char* fgb = (const char*)fgs[rel] + lane * 4;
            const float* wrow = wts[wid][lane >> 5];
            const uint* sorow = soff[wid];
            int tt = 0;
            for (; tt + 4 <= deg; tt += 4) {
                const uint o0 = sorow[tt],     o1 = sorow[tt + 1];
                const uint o2 = sorow[tt + 2], o3 = sorow[tt + 3];
                const float w0 = wrow[tt],     w1 = wrow[tt + 1];
                const float w2 = wrow[tt + 2], w3 = wrow[tt + 3];
                const uint u0 = *(const uint*)(fgb + o0);
                const uint u1 = *(const uint*)(fgb + o1);
                const uint u2 = *(const uint*)(fgb + o2);
                const uint u3 = *(const uint*)(fgb + o3);
                const float2 f0 = bfpair(u0), f1 = bfpair(u1);
                const float2 f2 = bfpair(u2), f3 = bfpair(u3);
                acc.x += f0.x * w0 + f1.x * w1 + f2.x * w2 + f3.x * w3;
                acc.y += f0.y * w0 + f1.y * w1 + f2.y * w2 + f3.y * w3;
            }
            for (; tt < deg; tt++) {
                const uint o0 = sorow[tt];
                const float w0 = wrow[tt];
                const float2 f0 = bfpair(*(const uint*)(fgb + o0));
                acc.x += f0.x * w0;
                acc.y += f0.y * w0;
            }
        } else {
            float den0 = 0.f, den1 = 0.f;
            for (int c0 = beg; c0 < end; c0 += 64) {
                const int j = c0 + lane;
                if (j < end) {
                    const float2 e = els[rel][csrs[rel][j]];
                    float e0 = e.x + erd.x, e1 = e.y + erd.y;
                    e0 = e0 > 0.f ? e0 : 0.2f * e0;
                    e1 = e1 > 0.f ? e1 : 0.2f * e1;
                    den0 += __expf(e0);
                    den1 += __expf(e1);
                }
            }
            for (int o = 32; o > 0; o >>= 1) {
                den0 += __shfl_xor(den0, o);
                den1 += __shfl_xor(den1, o);
            }
            const float inv0 = 1.0f / den0, inv1 = 1.0f / den1;
            for (int c0 = beg; c0 < end; c0 += 64) {
                const int j = c0 + lane;
                int s = -1;
                float ex0 = 0.f, ex1 = 0.f;
                if (j < end) {
                    s = csrs[rel][j];
                    const float2 e = els[rel][s];
                    float e0 = e.x + erd.x, e1 = e.y + erd.y;
                    e0 = e0 > 0.f ? e0 : 0.2f * e0;
                    e1 = e1 > 0.f ? e1 : 0.2f * e1;
                    ex0 = __expf(e0) * inv0;
                    ex1 = __expf(e1) * inv1;
                }
                const int cm = min(64, end - c0);
                for (int tt = 0; tt < cm; tt++) {
                    const int st = __shfl(s, tt);
                    const float a0 = __shfl(ex0, tt);
                    const float a1 = __shfl(ex1, tt);
                    const float aa = (lane < 32) ? a0 : a1;
                    const float2 fv = bfpair(
                        *(const uint*)((const char*)fgs[rel] + ((size_t)st << 8) + lane * 4));
                    acc.x += fv.x * aa;
                    acc.y += fv.y * aa;
                }
            }
        }

        const float b0 = biases[rel][2 * lane], b1 = biases[rel][2 * lane + 1];
        oacc0 += elu(acc.x + b0);
        oacc1 += elu(acc.y + b1);
    }

    if (obf) {
        ushort tmp[2] = { f2bf(oacc0), f2bf(oacc1) };
        *(uint*)(outbf + (size_t)wv * DIM + 2 * lane) = *(const uint*)tmp;
    } else {
        float* op = outf + (size_t)wv * DIM + 2 * lane;
        op[0] = oacc0; op[1] = oacc1;
    }
}

extern "C" void kernel_launch(void* const* d_in, const int* in_sizes, int n_in,
                              void* d_out, int out_size, void* d_ws, size_t ws_size,
                              hipStream_t stream)
{
    const float* x   = (const float*)d_in[0];
    const float* W0  = (const float*)d_in[1];
    const float* al0 = (const float*)d_in[2];
    const float* ar0 = (const float*)d_in[3];
    const float* b0  = (const float*)d_in[4];
    const float* W1  = (const float*)d_in[5];
    const float* al1 = (const float*)d_in[6];
    const float* ar1 = (const float*)d_in[7];
    const float* b1  = (const float*)d_in[8];
    const int* src0 = (const int*)d_in[9];
    const int* dst0 = (const int*)d_in[10];
    const int* src1 = (const int*)d_in[11];
    const int* dst1 = (const int*)d_in[12];
    float* out = (float*)d_out;

    char* w = (char*)d_ws;
    auto alloc = [&](size_t bytes) {
        char* p = w; w += (bytes + 255) & ~(size_t)255; return p;
    };
    ushort* xbf    = (ushort*)alloc((size_t)NN * DIM * 2);
    ushort* h1bf   = (ushort*)alloc((size_t)NN * DIM * 2);
    ushort* fg0    = (ushort*)alloc((size_t)NN * DIM * 2);
    ushort* fg1    = (ushort*)alloc((size_t)NN * DIM * 2);
    ushort* WT     = (ushort*)alloc((size_t)4 * DIM * DIM * 2);
    float*  elb    = (float*)alloc((size_t)4 * NN * 2 * 4);  // el0,er0,el1,er1
    int*    row    = (int*)alloc((size_t)4 * (NN + 1) * 4);
    ushort* csr    = (ushort*)alloc((size_t)4 * NE * 2);
    uint*   binned = (uint*)alloc((size_t)4 * NE * 4);
    int*    bcount = (int*)alloc((size_t)4 * NB * 4);
    int*    bbase  = (int*)alloc((size_t)4 * (NB + 1) * 4);
    int*    gcur   = (int*)alloc((size_t)4 * NB * 4);
    float* el0p = elb;
    float* er0p = elb + (size_t)NN * 2;
    float* el1p = elb + (size_t)NN * 4;
    float* er1p = elb + (size_t)NN * 6;

    // ---- converts ----
    convert_x<<<(NN * DIM / 8 + 255) / 256, 256, 0, stream>>>(x, xbf, NN * DIM / 8);
    conv_wt<<<64, 256, 0, stream>>>(W0, W1, WT);

    // ---- CSR build ----
    hipMemsetAsync(bcount, 0, (size_t)4 * NB * 4, stream);
    {
        const int bpset = (NE + CH - 1) / CH;
        bucket_hist<<<4 * bpset, 256, 0, stream>>>(dst0, dst1, bcount);
        scan_buckets<<<1, 64, 0, stream>>>(bcount, bbase, gcur, row);
        bin_edges<<<4 * bpset, 256, 0, stream>>>(dst0, dst1, src0, src1, gcur, binned);
    }
    build_csr<<<4 * NB, 256, 0, stream>>>(bbase, binned, row, csr);

    const int gblocks = (NN + 63) / 64;
    for (int L = 0; L < 2; L++) {
        const ushort* hin = L ? h1bf : xbf;
        const ushort* WTl = WT + (size_t)L * 2 * DIM * DIM;
        const float* al  = L ? al1 : al0;
        const float* ar  = L ? ar1 : ar0;
        const float* b   = L ? b1 : b0;
        gemm_mfma<<<gblocks, 256, 0, stream>>>(
            hin, WTl, al, ar, fg0, el0p, er0p, NN);
        gemm_mfma<<<gblocks, 256, 0, stream>>>(
            hin, WTl + (size_t)DIM * DIM, al + DIM, ar + DIM, fg1, el1p, er1p, NN);
        const int es0 = L * 2, es1 = L * 2 + 1;
        aggregate_dual<<<(NN * 64 + 255) / 256, 256, 0, stream>>>(
            row + es0 * (NN + 1), csr + (size_t)es0 * NE,
            row + es1 * (NN + 1), csr + (size_t)es1 * NE,
            (const float2*)el0p, (const float2*)er0p,
            (const float2*)el1p, (const float2*)er1p,
            fg0, fg1, b, b + DIM,
            L ? out : nullptr, L ? nullptr : h1bf, L ? 0 : 1);
    }
}

// Round 11
// 367.106 us; speedup vs baseline: 9.0679x; 1.0804x over previous
//
#include <hip/hip_runtime.h>

#define NN 50000
#define NE 800000
#define DIM 128
#define NB 128          // dst buckets for binned CSR build
#define CH 4096         // edges per binning block
#define CAP 8192        // slots per bucket (mean 6250, sd 79 -> +24 sigma)

typedef unsigned int uint;
typedef unsigned short ushort;
typedef __attribute__((ext_vector_type(8))) short v8s;
typedef __attribute__((ext_vector_type(4))) float v4f;

__device__ __forceinline__ ushort f2bf(float f) {
    union { float f; uint i; } c; c.f = f;
    const uint r = (c.i + 0x7fffu + ((c.i >> 16) & 1u)) >> 16;
    return (ushort)r;
}

// WT[m][n][k] = bf16(W[m][k][n]); m: 0,1 from W0, 2,3 from W1.
__global__ __launch_bounds__(256) void conv_wt(
    const float* __restrict__ W0, const float* __restrict__ W1,
    ushort* __restrict__ WT)
{
    const int t = blockIdx.x * 256 + threadIdx.x;
#pragma unroll
    for (int i = 0; i < 4; i++) {
        const int o = t * 4 + i;                    // 0 .. 65535
        const int m = o >> 14, rem = o & 16383;
        const int nrow = rem >> 7, k = rem & 127;
        const float* src = (m < 2) ? (W0 + (size_t)m * 16384)
                                   : (W1 + (size_t)(m - 2) * 16384);
        WT[o] = f2bf(src[k * 128 + nrow]);
    }
}

// ---------------- dual-relation MFMA GEMM ----------------
// Block 256 = 4 waves; wave w: rows [b*64+16w,+16) x 128 cols, both relations.
// A loaded once (f32 path converts in-register). Epilogue: LDS-staged
// coalesced bf16 store + fused el/er reduction.
__global__ __launch_bounds__(256) void gemm_dual(
    const ushort* __restrict__ hbf, const float* __restrict__ xf,
    const ushort* __restrict__ WT,
    const float* __restrict__ al, const float* __restrict__ ar,
    ushort* __restrict__ fg0, ushort* __restrict__ fg1,
    float* __restrict__ elb, int n, int is_f32)
{
    __shared__ ushort tile[64][136];
    const int tid = threadIdx.x;
    const int w = tid >> 6, lane = tid & 63;
    const int quad = lane >> 4, l16 = lane & 15;
    const int row0 = blockIdx.x * 64 + w * 16;

    int arow = row0 + l16;
    if (arow >= n) arow = n - 1;   // clamp; OOB rows never stored

    v8s afr[4];
    if (is_f32) {
        const float* ap = xf + (size_t)arow * DIM + quad * 8;
#pragma unroll
        for (int kt = 0; kt < 4; kt++) {
            const float4 a0 = *(const float4*)(ap + kt * 32);
            const float4 a1 = *(const float4*)(ap + kt * 32 + 4);
            ushort tmp[8] = { f2bf(a0.x), f2bf(a0.y), f2bf(a0.z), f2bf(a0.w),
                              f2bf(a1.x), f2bf(a1.y), f2bf(a1.z), f2bf(a1.w) };
            afr[kt] = *(const v8s*)tmp;
        }
    } else {
        const ushort* ap = hbf + (size_t)arow * DIM + quad * 8;
#pragma unroll
        for (int kt = 0; kt < 4; kt++) afr[kt] = *(const v8s*)(ap + kt * 32);
    }

    for (int rel = 0; rel < 2; rel++) {
        const ushort* bp = WT + (size_t)rel * DIM * DIM + (size_t)l16 * DIM + quad * 8;
        v4f acc[8];
#pragma unroll
        for (int nt = 0; nt < 8; nt++) acc[nt] = (v4f)0.0f;
#pragma unroll
        for (int kt = 0; kt < 4; kt++) {
#pragma unroll
            for (int nt = 0; nt < 8; nt++) {
                const v8s b = *(const v8s*)(bp + (size_t)nt * 16 * DIM + kt * 32);
                acc[nt] = __builtin_amdgcn_mfma_f32_16x16x32_bf16(afr[kt], b, acc[nt], 0, 0, 0);
            }
        }

        // el/er: partial dot per lane, reduce across l16 within quad rows
        const float* alr = al + rel * DIM;
        const float* arr = ar + rel * DIM;
        float pel[4][2], per2[4][2];
#pragma unroll
        for (int r = 0; r < 4; r++)
            pel[r][0] = pel[r][1] = per2[r][0] = per2[r][1] = 0.f;
#pragma unroll
        for (int nt = 0; nt < 8; nt++) {
            const int col = nt * 16 + l16;
            const float av = alr[col], rv = arr[col];
            const int head = nt >> 2;
#pragma unroll
            for (int r = 0; r < 4; r++) {
                pel[r][head] += acc[nt][r] * av;
                per2[r][head] += acc[nt][r] * rv;
            }
        }
#pragma unroll
        for (int o = 1; o < 16; o <<= 1) {
#pragma unroll
            for (int r = 0; r < 4; r++) {
#pragma unroll
                for (int h = 0; h < 2; h++) {
                    pel[r][h] += __shfl_xor(pel[r][h], o);
                    per2[r][h] += __shfl_xor(per2[r][h], o);
                }
            }
        }
        float* elp = elb + (size_t)rel * NN * 4;
        float* erp = elp + (size_t)NN * 2;
        if (l16 == 0) {
#pragma unroll
            for (int r = 0; r < 4; r++) {
                const int row = row0 + quad * 4 + r;
                if (row < n) {
#pragma unroll
                    for (int h = 0; h < 2; h++) {
                        elp[row * 2 + h] = pel[r][h];
                        erp[row * 2 + h] = per2[r][h];
                    }
                }
            }
        }

        // coalesced bf16 store via LDS
        __syncthreads();   // prior rel's tile reads done
        const int lr0 = w * 16 + quad * 4;
#pragma unroll
        for (int nt = 0; nt < 8; nt++) {
            const int col = nt * 16 + l16;
#pragma unroll
            for (int r = 0; r < 4; r++)
                tile[lr0 + r][col] = f2bf(acc[nt][r]);
        }
        __syncthreads();
        ushort* fgr = rel ? fg1 : fg0;
        const int srow = tid >> 2, ch = tid & 3;   // 64 rows x 4 chunks of 32
        const int grow = blockIdx.x * 64 + srow;
        if (grow < n) {
            const uint4* lp = (const uint4*)&tile[srow][ch * 32];
            uint4* gp = (uint4*)(fgr + (size_t)grow * DIM + ch * 32);
            gp[0] = lp[0];
            gp[1] = lp[1];
            gp[2] = lp[2];
            gp[3] = lp[3];
        }
    }
}

// ---------------- CSR build (fixed-capacity buckets) ----------------
__global__ __launch_bounds__(512) void init_gcur(int* __restrict__ gcur)
{
    const int i = threadIdx.x;
    gcur[i] = i * CAP;
}

// Pass A: bin edges by dst bucket; payload packed (dst<<16)|src.
__global__ __launch_bounds__(256) void bin_edges(
    const int* __restrict__ dst0, const int* __restrict__ dst1,
    const int* __restrict__ src0, const int* __restrict__ src1,
    int* __restrict__ gcur, uint* __restrict__ binned)
{
    __shared__ int hist[NB], ebase[NB], lcur[NB], gbase[NB], sc[NB];
    __shared__ uint stage[CH];
    const int bpset = (NE + CH - 1) / CH;
    const int bid = blockIdx.x;
    const int s = bid / bpset, cb = bid - s * bpset;
    const int* dstp = (s < 2) ? (dst0 + (size_t)s * NE) : (dst1 + (size_t)(s - 2) * NE);
    const int* srcp = (s < 2) ? (src0 + (size_t)s * NE) : (src1 + (size_t)(s - 2) * NE);
    const int e0 = cb * CH;
    const int t = threadIdx.x;

    if (t < NB) hist[t] = 0;
    __syncthreads();

    int myd[16], mys[16];
#pragma unroll
    for (int k = 0; k < 16; k++) {
        const int e = e0 + t + k * 256;
        if (e < NE) {
            const int d = dstp[e];
            myd[k] = d;
            mys[k] = srcp[e];
            atomicAdd(&hist[(d * NB) / NN], 1);
        } else myd[k] = -1;
    }
    __syncthreads();
    if (t < NB) sc[t] = hist[t];
    __syncthreads();
    for (int o = 1; o < NB; o <<= 1) {
        int tv = 0;
        if (t < NB && t >= o) tv = sc[t - o];
        __syncthreads();
        if (t < NB) sc[t] += tv;
        __syncthreads();
    }
    if (t < NB) {
        ebase[t] = sc[t] - hist[t];
        lcur[t]  = sc[t] - hist[t];
        gbase[t] = atomicAdd(&gcur[s * NB + t], hist[t]);
    }
    __syncthreads();
#pragma unroll
    for (int k = 0; k < 16; k++) {
        if (myd[k] >= 0) {
            const int b = (myd[k] * NB) / NN;
            const int p = atomicAdd(&lcur[b], 1);
            stage[p] = ((uint)myd[k] << 16) | (uint)mys[k];
        }
    }
    __syncthreads();
    const int total = ebase[NB - 1] + hist[NB - 1];
    for (int i = t; i < total; i += 256) {
        const uint v = stage[i];
        const int b = ((int)(v >> 16) * NB) / NN;
        binned[gbase[b] + (i - ebase[b])] = v;   // gbase is absolute (slotted)
    }
}

// post-scan: packed per-set bucket bases from gcur fill levels.
__global__ __launch_bounds__(64) void scan_buckets(
    const int* __restrict__ gcur, int* __restrict__ bbase, int* __restrict__ row)
{
    const int s = threadIdx.x;
    if (s < 4) {
        int acc = 0;
        for (int b = 0; b < NB; b++) {
            bbase[s * (NB + 1) + b] = acc;
            acc += gcur[s * NB + b] - (s * NB + b) * CAP;
        }
        bbase[s * (NB + 1) + NB] = acc;   // == NE
        row[s * (NN + 1) + NN] = NE;
    }
}

// Pass B: per (set,bucket): LDS degree count + scan -> row[] + ushort csr.
__global__ __launch_bounds__(256) void build_csr(
    const int* __restrict__ bbase, const uint* __restrict__ binned,
    int* __restrict__ row, ushort* __restrict__ csr_src)
{
    __shared__ int A[512], B[512], lcur[512];
    const int bid = blockIdx.x;
    const int s = bid >> 7, b = bid & (NB - 1);
    const int nb0 = (b * NN + NB - 1) / NB;
    int nb1 = ((b + 1) * NN + NB - 1) / NB;
    if (nb1 > NN) nb1 = NN;
    const int nloc = nb1 - nb0;
    const int jb = bbase[s * (NB + 1) + b], je = bbase[s * (NB + 1) + b + 1];
    const int cnt = je - jb;
    const uint* bslot = binned + (size_t)(s * NB + b) * CAP;
    const int t = threadIdx.x;

    A[t] = 0; A[t + 256] = 0;
    __syncthreads();
    for (int j = t; j < cnt; j += 256)
        atomicAdd(&A[(int)(bslot[j] >> 16) - nb0], 1);
    __syncthreads();
    const int c0 = A[t], c1 = A[t + 256];
    int* cur = A; int* nxt = B;
    for (int off = 1; off < 512; off <<= 1) {
        nxt[t]       = cur[t]       + ((t >= off)       ? cur[t - off]       : 0);
        nxt[t + 256] = cur[t + 256] + ((t + 256 >= off) ? cur[t + 256 - off] : 0);
        __syncthreads();
        int* tmp = cur; cur = nxt; nxt = tmp;
    }
    if (t < nloc) {
        const int v = jb + cur[t] - c0;
        lcur[t] = v;
        row[s * (NN + 1) + nb0 + t] = v;
    }
    if (t + 256 < nloc) {
        const int v = jb + cur[t + 256] - c1;
        lcur[t + 256] = v;
        row[s * (NN + 1) + nb0 + t + 256] = v;
    }
    __syncthreads();
    ushort* outp = csr_src + (size_t)s * NE;
    for (int j = t; j < cnt; j += 256) {
        const uint v = bslot[j];
        const int p = atomicAdd(&lcur[(int)(v >> 16) - nb0], 1);
        outp[p] = (ushort)(v & 0xffffu);
    }
}

__device__ __forceinline__ float elu(float v) { return v > 0.f ? v : expm1f(v); }
__device__ __forceinline__ float2 bfpair(uint u) {
    union { uint i; float f; } lo, hi;
    lo.i = u << 16;
    hi.i = u & 0xffff0000u;
    return make_float2(lo.f, hi.f);
}

// ---------------- dual-relation fused softmax + aggregate -------------------
__global__ __launch_bounds__(256) void aggregate_dual(
    const int* __restrict__ row0, const ushort* __restrict__ csr0,
    const int* __restrict__ row1, const ushort* __restrict__ csr1,
    const float2* __restrict__ el0, const float2* __restrict__ er0,
    const float2* __restrict__ el1, const float2* __restrict__ er1,
    const ushort* __restrict__ fg0, const ushort* __restrict__ fg1,
    const float* __restrict__ bias0, const float* __restrict__ bias1,
    float* __restrict__ outf, ushort* __restrict__ outbf, int obf)
{
    __shared__ uint soff[4][64];
    __shared__ float wts[4][2][64];
    const int wv = (blockIdx.x * 256 + threadIdx.x) >> 6;
    if (wv >= NN) return;
    const int lane = threadIdx.x & 63;
    const int wid = threadIdx.x >> 6;

    const int* rows[2] = {row0, row1};
    const ushort* csrs[2] = {csr0, csr1};
    const float2* els[2] = {el0, el1};
    const float2* ers[2] = {er0, er1};
    const ushort* fgs[2] = {fg0, fg1};
    const float* biases[2] = {bias0, bias1};

    float oacc0 = 0.f, oacc1 = 0.f;

#pragma unroll
    for (int rel = 0; rel < 2; rel++) {
        const int beg = rows[rel][wv], end = rows[rel][wv + 1];
        const int deg = end - beg;
        const float2 erd = ers[rel][wv];
        float2 acc = make_float2(0.f, 0.f);

        if (deg <= 64) {
            uint sof = 0;
            float ex0 = 0.f, ex1 = 0.f;
            if (lane < deg) {
                const int s = csrs[rel][beg + lane];
                const float2 e = els[rel][s];
                float e0 = e.x + erd.x, e1 = e.y + erd.y;
                e0 = e0 > 0.f ? e0 : 0.2f * e0;
                e1 = e1 > 0.f ? e1 : 0.2f * e1;
                ex0 = __expf(e0);
                ex1 = __expf(e1);
                sof = (uint)s << 8;
            }
            float den0 = ex0, den1 = ex1;
            for (int o = 32; o > 0; o >>= 1) {
                den0 += __shfl_xor(den0, o);
                den1 += __shfl_xor(den1, o);
            }
            const float inv0 = 1.0f / den0, inv1 = 1.0f / den1;
            soff[wid][lane] = sof;
            wts[wid][0][lane] = ex0 * inv0;
            wts[wid][1][lane] = ex1 * inv1;
            const char* fgb = (const char*)fgs[rel] + lane * 4;
            const float* wrow = wts[wid][lane >> 5];
            const uint* sorow = soff[wid];
            int tt = 0;
            for (; tt + 4 <= deg; tt += 4) {
                const uint o0 = sorow[tt],     o1 = sorow[tt + 1];
                const uint o2 = sorow[tt + 2], o3 = sorow[tt + 3];
                const float w0 = wrow[tt],     w1 = wrow[tt + 1];
                const float w2 = wrow[tt + 2], w3 = wrow[tt + 3];
                const uint u0 = *(const uint*)(fgb + o0);
                const uint u1 = *(const uint*)(fgb + o1);
                const uint u2 = *(const uint*)(fgb + o2);
                const uint u3 = *(const uint*)(fgb + o3);
                const float2 f0 = bfpair(u0), f1 = bfpair(u1);
                const float2 f2 = bfpair(u2), f3 = bfpair(u3);
                acc.x += f0.x * w0 + f1.x * w1 + f2.x * w2 + f3.x * w3;
                acc.y += f0.y * w0 + f1.y * w1 + f2.y * w2 + f3.y * w3;
            }
            for (; tt < deg; tt++) {
                const uint o0 = sorow[tt];
                const float w0 = wrow[tt];
                const float2 f0 = bfpair(*(const uint*)(fgb + o0));
                acc.x += f0.x * w0;
                acc.y += f0.y * w0;
            }
        } else {
            float den0 = 0.f, den1 = 0.f;
            for (int c0 = beg; c0 < end; c0 += 64) {
                const int j = c0 + lane;
                if (j < end) {
                    const float2 e = els[rel][csrs[rel][j]];
                    float e0 = e.x + erd.x, e1 = e.y + erd.y;
                    e0 = e0 > 0.f ? e0 : 0.2f * e0;
                    e1 = e1 > 0.f ? e1 : 0.2f * e1;
                    den0 += __expf(e0);
                    den1 += __expf(e1);
                }
            }
            for (int o = 32; o > 0; o >>= 1) {
                den0 += __shfl_xor(den0, o);
                den1 += __shfl_xor(den1, o);
            }
            const float inv0 = 1.0f / den0, inv1 = 1.0f / den1;
            for (int c0 = beg; c0 < end; c0 += 64) {
                const int j = c0 + lane;
                int s = -1;
                float ex0 = 0.f, ex1 = 0.f;
                if (j < end) {
                    s = csrs[rel][j];
                    const float2 e = els[rel][s];
                    float e0 = e.x + erd.x, e1 = e.y + erd.y;
                    e0 = e0 > 0.f ? e0 : 0.2f * e0;
                    e1 = e1 > 0.f ? e1 : 0.2f * e1;
                    ex0 = __expf(e0) * inv0;
                    ex1 = __expf(e1) * inv1;
                }
                const int cm = min(64, end - c0);
                for (int tt = 0; tt < cm; tt++) {
                    const int st = __shfl(s, tt);
                    const float a0 = __shfl(ex0, tt);
                    const float a1 = __shfl(ex1, tt);
                    const float aa = (lane < 32) ? a0 : a1;
                    const float2 fv = bfpair(
                        *(const uint*)((const char*)fgs[rel] + ((size_t)st << 8) + lane * 4));
                    acc.x += fv.x * aa;
                    acc.y += fv.y * aa;
                }
            }
        }

        const float b0 = biases[rel][2 * lane], b1 = biases[rel][2 * lane + 1];
        oacc0 += elu(acc.x + b0);
        oacc1 += elu(acc.y + b1);
    }

    if (obf) {
        ushort tmp[2] = { f2bf(oacc0), f2bf(oacc1) };
        *(uint*)(outbf + (size_t)wv * DIM + 2 * lane) = *(const uint*)tmp;
    } else {
        float* op = outf + (size_t)wv * DIM + 2 * lane;
        op[0] = oacc0; op[1] = oacc1;
    }
}

extern "C" void kernel_launch(void* const* d_in, const int* in_sizes, int n_in,
                              void* d_out, int out_size, void* d_ws, size_t ws_size,
                              hipStream_t stream)
{
    const float* x   = (const float*)d_in[0];
    const float* W0  = (const float*)d_in[1];
    const float* al0 = (const float*)d_in[2];
    const float* ar0 = (const float*)d_in[3];
    const float* b0  = (const float*)d_in[4];
    const float* W1  = (const float*)d_in[5];
    const float* al1 = (const float*)d_in[6];
    const float* ar1 = (const float*)d_in[7];
    const float* b1  = (const float*)d_in[8];
    const int* src0 = (const int*)d_in[9];
    const int* dst0 = (const int*)d_in[10];
    const int* src1 = (const int*)d_in[11];
    const int* dst1 = (const int*)d_in[12];
    float* out = (float*)d_out;

    char* w = (char*)d_ws;
    auto alloc = [&](size_t bytes) {
        char* p = w; w += (bytes + 255) & ~(size_t)255; return p;
    };
    ushort* h1bf   = (ushort*)alloc((size_t)NN * DIM * 2);
    ushort* fg0    = (ushort*)alloc((size_t)NN * DIM * 2);
    ushort* fg1    = (ushort*)alloc((size_t)NN * DIM * 2);
    ushort* WT     = (ushort*)alloc((size_t)4 * DIM * DIM * 2);
    float*  elb    = (float*)alloc((size_t)8 * NN * 4);      // el0,er0,el1,er1
    int*    row    = (int*)alloc((size_t)4 * (NN + 1) * 4);
    ushort* csr    = (ushort*)alloc((size_t)4 * NE * 2);
    uint*   binned = (uint*)alloc((size_t)4 * NB * CAP * 4); // slotted
    int*    bbase  = (int*)alloc((size_t)4 * (NB + 1) * 4);
    int*    gcur   = (int*)alloc((size_t)4 * NB * 4);

    // ---- one-time prep ----
    conv_wt<<<64, 256, 0, stream>>>(W0, W1, WT);
    init_gcur<<<1, 512, 0, stream>>>(gcur);
    {
        const int bpset = (NE + CH - 1) / CH;
        bin_edges<<<4 * bpset, 256, 0, stream>>>(dst0, dst1, src0, src1, gcur, binned);
    }
    scan_buckets<<<1, 64, 0, stream>>>(gcur, bbase, row);
    build_csr<<<4 * NB, 256, 0, stream>>>(bbase, binned, row, csr);

    const int gblocks = (NN + 63) / 64;
    for (int L = 0; L < 2; L++) {
        const ushort* WTl = WT + (size_t)L * 2 * DIM * DIM;
        const float* al  = L ? al1 : al0;
        const float* ar  = L ? ar1 : ar0;
        const float* b   = L ? b1 : b0;
        gemm_dual<<<gblocks, 256, 0, stream>>>(
            L ? h1bf : nullptr, L ? nullptr : x, WTl, al, ar,
            fg0, fg1, elb, NN, L ? 0 : 1);
        const int es0 = L * 2, es1 = L * 2 + 1;
        float* el0p = elb;
        float* er0p = elb + (size_t)NN * 2;
        float* el1p = elb + (size_t)NN * 4;
        float* er1p = elb + (size_t)NN * 6;
        aggregate_dual<<<(NN * 64 + 255) / 256, 256, 0, stream>>>(
            row + es0 * (NN + 1), csr + (size_t)es0 * NE,
            row + es1 * (NN + 1), csr + (size_t)es1 * NE,
            (const float2*)el0p, (const float2*)er0p,
            (const float2*)el1p, (const float2*)er1p,
            fg0, fg1, b, b + DIM,
            L ? out : nullptr, L ? nullptr : h1bf, L ? 0 : 1);
    }
}